// Round 3
// baseline (748.599 us; speedup 1.0000x reference)
//
#include <hip/hip_runtime.h>
#include <stdint.h>

// ---------------- common helpers ----------------

using f32x4 = __attribute__((ext_vector_type(4))) float;
using s16x8 = __attribute__((ext_vector_type(8))) short;

__device__ __forceinline__ ushort f2b(float f) {
    union { float f; uint32_t u; } v; v.f = f;
    uint32_t u = v.u;
    return (ushort)((u + 0x7fffu + ((u >> 16) & 1u)) >> 16);
}
__device__ __forceinline__ float b2f(ushort b) {
    union { uint32_t u; float f; } v; v.u = ((uint32_t)b) << 16;
    return v.f;
}
__device__ __forceinline__ float to_f(float f) { return f; }
__device__ __forceinline__ float to_f(ushort b) { return b2f(b); }

// async global->LDS, 16B per lane; LDS dest = wave-uniform base + lane*16
__device__ __forceinline__ void async_ld16(const ushort* g, ushort* l) {
    __builtin_amdgcn_global_load_lds(
        (const __attribute__((address_space(1))) void*)g,
        (__attribute__((address_space(3))) void*)l,
        16, 0, 0);
}

// ---------------- cast fp32 -> bf16 (vectorized x4) ----------------

__global__ __launch_bounds__(256) void cast_f2b4(const float* __restrict__ src,
                                                 ushort* __restrict__ dst,
                                                 long long n4) {
    long long i = (long long)blockIdx.x * 256 + threadIdx.x;
    if (i >= n4) return;
    float4 f = ((const float4*)src)[i];
    ushort4 o;
    o.x = f2b(f.x); o.y = f2b(f.y); o.z = f2b(f.z); o.w = f2b(f.w);
    ((ushort4*)dst)[i] = o;
}

// ---------------- zero fill (float4) ----------------

__global__ __launch_bounds__(256) void zero_f4(float* __restrict__ dst, long long n4) {
    long long i = (long long)blockIdx.x * 256 + threadIdx.x;
    if (i >= n4) return;
    ((float4*)dst)[i] = (float4){0.f, 0.f, 0.f, 0.f};
}

// ---------------- transpose (fp32 or bf16 in) -> bf16 out ----------------
// src: [R][C] with row stride srcLd, dst: [C][R] row-major.
// Grid: (C/32, R/32, batch), block (32,8).

template <typename T>
__global__ __launch_bounds__(256) void transpose_to_bf16(const T* __restrict__ src,
                                                         ushort* __restrict__ dst,
                                                         int R, int C, int srcLd,
                                                         long long ss, long long ds) {
    __shared__ float tile[32][33];
    src += (long long)blockIdx.z * ss;
    dst += (long long)blockIdx.z * ds;
    const int c0 = blockIdx.x * 32;
    const int r0 = blockIdx.y * 32;
    const int tx = threadIdx.x, ty = threadIdx.y;
#pragma unroll
    for (int i = 0; i < 4; i++) {
        int r = r0 + ty + i * 8;
        tile[ty + i * 8][tx] = to_f(src[(long long)r * srcLd + c0 + tx]);
    }
    __syncthreads();
#pragma unroll
    for (int i = 0; i < 4; i++) {
        int r = c0 + ty + i * 8;  // row of dst, in [0, C)
        dst[(long long)r * R + r0 + tx] = f2b(tile[tx][ty + i * 8]);
    }
}

// ---------------- bf16 MFMA GEMM:  C[M,N] = A[M,K] * BT[N,K]^T (+bias, relu, scale) ----
// 128x128 tile per 256-thread block (4 waves, each 64x64 = 4x4 MFMA 16x16x32 tiles).
// Staging via global_load_lds width=16 (m97 structure): UNPADDED LDS [row][32],
// wave w instr i covers rows w*32+i*16..+16; lane l -> row +(l>>2), col (l&3)*8.
// Grid: (N/128, M/128, batch*kChunks). gridDim.y must be a multiple of 8 (XCD swizzle).
// Split-K (kChunks>1): blockIdx.z = batch*kChunks + kIdx; partials atomically added
// into pre-zeroed fp32 C; bias added by chunk 0 only.

#define BM 128
#define BN 128
#define BKK 32

template <int OUT_BF16, int RELU, int HAS_BIAS, int ATOMIC>
__global__ __launch_bounds__(256) void gemm_bt(const ushort* __restrict__ A,
                                               const ushort* __restrict__ BT,
                                               void* __restrict__ Cp,
                                               const float* __restrict__ bias,
                                               int N, int K, int kChunks, float scale,
                                               int lda, int ldb, int ldc,
                                               long long sA, long long sB, long long sC) {
    __shared__ ushort As[BM * BKK];
    __shared__ ushort Bs[BN * BKK];

    const int tid = threadIdx.x;
    const int kIdx = blockIdx.z % kChunks;
    const int bz = blockIdx.z / kChunks;
    const int kLen = K / kChunks;
    const int kOff = kIdx * kLen;
    const ushort* Ab = A + (long long)bz * sA;
    const ushort* Bb = BT + (long long)bz * sB;

    // XCD-panel swizzle: blocks with the same (linear id % 8) -> same XCD (heuristic).
    // Give each XCD a contiguous Hp-row panel, iterated column-major for B-tile reuse.
    const int W = gridDim.x, H = gridDim.y;
    const int b = blockIdx.y * W + blockIdx.x;
    const int Hp = H >> 3;
    const int xcd = b & 7;
    const int s = b >> 3;
    const int tn = s / Hp;
    const int tm = xcd * Hp + (s % Hp);

    const int lane = tid & 63;
    const int wave = tid >> 6;
    const int wm = (wave >> 1) * 64;
    const int wn = (wave & 1) * 64;
    const int quad = lane >> 4;
    const int l16 = lane & 15;

    // async staging addresses: wave covers rows [wave*32, wave*32+32)
    const int srow = wave * 32 + (lane >> 2);  // instr 1 adds 16 rows
    const int scol = (lane & 3) * 8;
    const ushort* AgL = Ab + (long long)(tm * BM + srow) * lda + scol + kOff;
    const ushort* BgL = Bb + (long long)(tn * BN + srow) * ldb + scol + kOff;
    ushort* AsL = As + wave * 1024;  // wave*2048 bytes; instr 1 adds 512 elems
    ushort* BsL = Bs + wave * 1024;
    const long long rstepA = (long long)16 * lda;
    const long long rstepB = (long long)16 * ldb;

    f32x4 acc[4][4];
#pragma unroll
    for (int i = 0; i < 4; i++)
#pragma unroll
        for (int j = 0; j < 4; j++) acc[i][j] = (f32x4){0.f, 0.f, 0.f, 0.f};

    for (int k0 = 0; k0 < kLen; k0 += BKK) {
        async_ld16(AgL + k0, AsL);
        async_ld16(AgL + rstepA + k0, AsL + 512);
        async_ld16(BgL + k0, BsL);
        async_ld16(BgL + rstepB + k0, BsL + 512);
        __syncthreads();  // compiler emits s_waitcnt vmcnt(0) before s_barrier

        s16x8 af[4], bf[4];
#pragma unroll
        for (int i = 0; i < 4; i++)
            af[i] = *(const s16x8*)&As[(wm + i * 16 + l16) * BKK + quad * 8];
#pragma unroll
        for (int j = 0; j < 4; j++)
            bf[j] = *(const s16x8*)&Bs[(wn + j * 16 + l16) * BKK + quad * 8];
#pragma unroll
        for (int i = 0; i < 4; i++)
#pragma unroll
            for (int j = 0; j < 4; j++)
                acc[i][j] = __builtin_amdgcn_mfma_f32_16x16x32_bf16(af[i], bf[j], acc[i][j], 0, 0, 0);
        __syncthreads();
    }

    // epilogue: C/D layout col = lane&15, row = quad*4 + reg  [verified m89/m91]
    const long long cb = (long long)bz * sC;
    float* Cf = (float*)Cp;
    ushort* Cb = (ushort*)Cp;
#pragma unroll
    for (int j = 0; j < 4; j++) {
        const int col = tn * BN + wn + j * 16 + l16;
        float bv = (HAS_BIAS && (!ATOMIC || kIdx == 0)) ? bias[col] : 0.0f;
#pragma unroll
        for (int i = 0; i < 4; i++) {
            const int row0 = tm * BM + wm + i * 16 + quad * 4;
#pragma unroll
            for (int r = 0; r < 4; r++) {
                float v = acc[i][j][r] * scale + bv;
                if (RELU) v = v > 0.f ? v : 0.f;
                long long idx = cb + (long long)(row0 + r) * ldc + col;
                if (ATOMIC) unsafeAtomicAdd(&Cf[idx], v);
                else if (OUT_BF16) Cb[idx] = f2b(v);
                else Cf[idx] = v;
            }
        }
    }
}

// ---------------- row softmax: fp32 [rows][2048] -> bf16 ----------------

__global__ __launch_bounds__(256) void softmax_rows(const float* __restrict__ S,
                                                    ushort* __restrict__ P) {
    const int C = 2048;
    const long long row = blockIdx.x;
    const float* s = S + row * C;
    ushort* p = P + row * C;
    const int tid = threadIdx.x;
    float v[8];
    float mx = -1e30f;
#pragma unroll
    for (int i = 0; i < 8; i++) {
        v[i] = s[tid + i * 256];
        mx = fmaxf(mx, v[i]);
    }
    __shared__ float red[256];
    red[tid] = mx;
    __syncthreads();
    for (int off = 128; off > 0; off >>= 1) {
        if (tid < off) red[tid] = fmaxf(red[tid], red[tid + off]);
        __syncthreads();
    }
    mx = red[0];
    __syncthreads();
    float sum = 0.f;
#pragma unroll
    for (int i = 0; i < 8; i++) {
        v[i] = __expf(v[i] - mx);
        sum += v[i];
    }
    red[tid] = sum;
    __syncthreads();
    for (int off = 128; off > 0; off >>= 1) {
        if (tid < off) red[tid] += red[tid + off];
        __syncthreads();
    }
    float inv = 1.f / red[0];
#pragma unroll
    for (int i = 0; i < 8; i++) p[tid + i * 256] = f2b(v[i] * inv);
}

// ---------------- fused residual + LayerNorm (D=1024), fp32 out + optional bf16 out ----

__global__ __launch_bounds__(256) void residual_ln(const float* __restrict__ X,
                                                   const float* __restrict__ Y,
                                                   const float* __restrict__ g,
                                                   const float* __restrict__ be,
                                                   float* __restrict__ outf,
                                                   ushort* __restrict__ outb) {
    const int D = 1024;
    const long long row = blockIdx.x;
    const float* x = X + row * D;
    const float* y = Y + row * D;
    const int tid = threadIdx.x;
    float v[4];
    float s = 0.f, s2 = 0.f;
#pragma unroll
    for (int i = 0; i < 4; i++) {
        int c = tid + i * 256;
        float t = x[c] + y[c];
        v[i] = t;
        s += t;
        s2 += t * t;
    }
    __shared__ float r1[256], r2[256];
    r1[tid] = s;
    r2[tid] = s2;
    __syncthreads();
    for (int off = 128; off > 0; off >>= 1) {
        if (tid < off) {
            r1[tid] += r1[tid + off];
            r2[tid] += r2[tid + off];
        }
        __syncthreads();
    }
    float mu = r1[0] * (1.f / 1024.f);
    float var = r2[0] * (1.f / 1024.f) - mu * mu;
    float inv = rsqrtf(var + 1e-5f);
    float* of = outf + row * D;
    ushort* ob = outb ? outb + row * D : nullptr;
#pragma unroll
    for (int i = 0; i < 4; i++) {
        int c = tid + i * 256;
        float o = (v[i] - mu) * inv * g[c] + be[c];
        of[c] = o;
        if (ob) ob[c] = f2b(o);
    }
}

// ---------------- launch ----------------

extern "C" void kernel_launch(void* const* d_in, const int* in_sizes, int n_in,
                              void* d_out, int out_size, void* d_ws, size_t ws_size,
                              hipStream_t stream) {
    const float* x  = (const float*)d_in[0];
    const float* wq = (const float*)d_in[1];
    const float* bq = (const float*)d_in[2];
    const float* wk = (const float*)d_in[3];
    const float* bk = (const float*)d_in[4];
    const float* wv = (const float*)d_in[5];
    const float* bv = (const float*)d_in[6];
    const float* wo = (const float*)d_in[7];
    const float* bo = (const float*)d_in[8];
    const float* w1 = (const float*)d_in[9];
    const float* b1 = (const float*)d_in[10];
    const float* w2 = (const float*)d_in[11];
    const float* b2 = (const float*)d_in[12];
    const float* g1 = (const float*)d_in[13];
    const float* be1 = (const float*)d_in[14];
    const float* g2 = (const float*)d_in[15];
    const float* be2 = (const float*)d_in[16];
    float* out = (float*)d_out;
    char* ws = (char*)d_ws;

    const int Bz = 4, S = 2048, D = 1024, F = 4096;
    const int T = Bz * S;  // 8192 rows
    const size_t MBy = 1024ull * 1024ull;

    // workspace layout (byte offsets), lifetime-based reuse; peak 200 MB
    ushort* xb   = (ushort*)(ws + 0);        // 16 MB  bf16 x
    ushort* qkvT = (ushort*)(ws + 16 * MBy); // 6 MB   [3072][1024] fused wq/wk/wv^T
    ushort* woT  = (ushort*)(ws + 22 * MBy); // 2 MB
    ushort* w1T  = (ushort*)(ws + 24 * MBy); // 8 MB   [F][D]
    ushort* w2T  = (ushort*)(ws + 32 * MBy); // 8 MB   [D][F]
    ushort* qkv  = (ushort*)(ws + 40 * MBy); // 48 MB  [T][3072] bf16 (q|k|v)
    ushort* vT   = (ushort*)(ws + 88 * MBy); // 16 MB  [B][D][S]
    float*  bqkv = (float*)(ws + 104 * MBy); // 12 KB  fused bias (dead before sc)
    float*  sc   = (float*)(ws + 104 * MBy); // 64 MB  scores fp32
    ushort* attn = (ushort*)(ws + 168 * MBy); // 32 MB
    // reuse (non-overlapping lifetimes):
    ushort* ctx = (ushort*)(ws + 40 * MBy);  // over qkv (dead after scores/vT)
    float*  ao  = (float*)(ws + 104 * MBy);  // over sc (dead after softmax)
    float*  x1  = (float*)(ws + 56 * MBy);   // over qkv k/v part (dead)
    ushort* x1b = (ushort*)(ws + 88 * MBy);  // over vT (dead after ctx)
    ushort* h   = (ushort*)(ws + 104 * MBy); // over sc/ao (ao dead after ln1)
    float*  ff  = (float*)(ws + 168 * MBy);  // over attn (dead after ctx)

    dim3 b32(32, 8);

    // 1) cast x -> bf16
    cast_f2b4<<<(T * D) / 1024, 256, 0, stream>>>(x, xb, (long long)(T * D) / 4);

    // 2) transpose-cast weights: wq/wk/wv stacked into qkvT [3072][1024]
    transpose_to_bf16<float><<<dim3(32, 32, 1), b32, 0, stream>>>(wq, qkvT, D, D, D, 0, 0);
    transpose_to_bf16<float><<<dim3(32, 32, 1), b32, 0, stream>>>(wk, qkvT + 1024 * 1024, D, D, D, 0, 0);
    transpose_to_bf16<float><<<dim3(32, 32, 1), b32, 0, stream>>>(wv, qkvT + 2048 * 1024, D, D, D, 0, 0);
    transpose_to_bf16<float><<<dim3(32, 32, 1), b32, 0, stream>>>(wo, woT, D, D, D, 0, 0);
    transpose_to_bf16<float><<<dim3(128, 32, 1), b32, 0, stream>>>(w1, w1T, D, F, F, 0, 0);
    transpose_to_bf16<float><<<dim3(32, 128, 1), b32, 0, stream>>>(w2, w2T, F, D, D, 0, 0);

    // 3) fused bias vector [bq|bk|bv]
    hipMemcpyAsync(bqkv, bq, D * sizeof(float), hipMemcpyDeviceToDevice, stream);
    hipMemcpyAsync(bqkv + D, bk, D * sizeof(float), hipMemcpyDeviceToDevice, stream);
    hipMemcpyAsync(bqkv + 2 * D, bv, D * sizeof(float), hipMemcpyDeviceToDevice, stream);

    // 4) fused QKV projection: [T][1024] x [3072][1024]^T -> [T][3072] bf16 (1536 blocks)
    gemm_bt<1, 0, 1, 0><<<dim3(3 * D / 128, T / 128, 1), 256, 0, stream>>>(
        xb, qkvT, qkv, bqkv, 3 * D, D, 1, 1.f, D, D, 3 * D, 0, 0, 0);

    // 5) V^T per batch: qkv v-slice [S][1024] (ld 3072) -> [D][S]
    transpose_to_bf16<ushort><<<dim3(D / 32, S / 32, Bz), b32, 0, stream>>>(
        qkv + 2048, vT, S, D, 3 * D, (long long)S * 3 * D, (long long)S * D);

    // 6) scores = Q K^T / 32 (fp32); A=q, B=k slices of qkv (ld 3072)
    gemm_bt<0, 0, 0, 0><<<dim3(S / 128, S / 128, Bz), 256, 0, stream>>>(
        qkv, qkv + 1024, sc, nullptr, S, D, 1, 0.03125f, 3 * D, 3 * D, S,
        (long long)S * 3 * D, (long long)S * 3 * D, (long long)S * S);

    // 7) softmax rows -> bf16 attn
    softmax_rows<<<T, 256, 0, stream>>>(sc, attn);

    // 8) zero ao (wo split-K accumulator)
    zero_f4<<<(T * D) / 1024, 256, 0, stream>>>(ao, (long long)(T * D) / 4);

    // 9) ctx = attn @ V  (BT = V^T [D][S]) -> bf16 [S][D] per batch
    gemm_bt<1, 0, 0, 0><<<dim3(D / 128, S / 128, Bz), 256, 0, stream>>>(
        attn, vT, ctx, nullptr, D, S, 1, 1.f, S, S, D,
        (long long)S * S, (long long)D * S, (long long)S * D);

    // 10) attn_out = ctx @ wo^T + bo, split-K=2, fp32 atomic (1024 blocks)
    gemm_bt<0, 0, 1, 1><<<dim3(D / 128, T / 128, 2), 256, 0, stream>>>(
        ctx, woT, ao, bo, D, D, 2, 1.f, D, D, D, 0, 0, 0);

    // 11) x1 = LN(x + ao) -> fp32 + bf16
    residual_ln<<<T, 256, 0, stream>>>(x, ao, g1, be1, x1, x1b);

    // 12) zero ff (FFN2 split-K accumulator)
    zero_f4<<<(T * D) / 1024, 256, 0, stream>>>(ff, (long long)(T * D) / 4);

    // 13) h = relu(x1 @ w1 + b1) (bf16)
    gemm_bt<1, 1, 1, 0><<<dim3(F / 128, T / 128, 1), 256, 0, stream>>>(
        x1b, w1T, h, b1, F, D, 1, 1.f, D, D, F, 0, 0, 0);

    // 14) ff = h @ w2 + b2, split-K=4 (chunks of 1024), fp32 atomic (2048 blocks)
    gemm_bt<0, 0, 1, 1><<<dim3(D / 128, T / 128, 4), 256, 0, stream>>>(
        h, w2T, ff, b2, D, F, 4, 1.f, F, F, D, 0, 0, 0);

    // 15) out = LN(x1 + ff) -> d_out fp32
    residual_ln<<<T, 256, 0, stream>>>(x1, ff, g2, be2, out, nullptr);
}

// Round 4
// 661.125 us; speedup vs baseline: 1.1323x; 1.1323x over previous
//
#include <hip/hip_runtime.h>
#include <stdint.h>

// ---------------- common helpers ----------------

using f32x4 = __attribute__((ext_vector_type(4))) float;
using s16x8 = __attribute__((ext_vector_type(8))) short;

__device__ __forceinline__ ushort f2b(float f) {
    union { float f; uint32_t u; } v; v.f = f;
    uint32_t u = v.u;
    return (ushort)((u + 0x7fffu + ((u >> 16) & 1u)) >> 16);
}
__device__ __forceinline__ float b2f(ushort b) {
    union { uint32_t u; float f; } v; v.u = ((uint32_t)b) << 16;
    return v.f;
}
__device__ __forceinline__ float to_f(float f) { return f; }
__device__ __forceinline__ float to_f(ushort b) { return b2f(b); }

// async global->LDS, 16B per lane; LDS dest = wave-uniform base + lane*16
__device__ __forceinline__ void async_ld16(const ushort* g, ushort* l) {
    __builtin_amdgcn_global_load_lds(
        (const __attribute__((address_space(1))) void*)g,
        (__attribute__((address_space(3))) void*)l,
        16, 0, 0);
}

// ---------------- cast fp32 -> bf16 (vectorized x4) ----------------

__global__ __launch_bounds__(256) void cast_f2b4(const float* __restrict__ src,
                                                 ushort* __restrict__ dst,
                                                 long long n4) {
    long long i = (long long)blockIdx.x * 256 + threadIdx.x;
    if (i >= n4) return;
    float4 f = ((const float4*)src)[i];
    ushort4 o;
    o.x = f2b(f.x); o.y = f2b(f.y); o.z = f2b(f.z); o.w = f2b(f.w);
    ((ushort4*)dst)[i] = o;
}

// ---------------- transpose (fp32 or bf16 in) -> bf16 out ----------------
// src: [R][C] with row stride srcLd, dst: [C][R] row-major.
// Grid: (C/32, R/32, batch), block (32,8).

template <typename T>
__global__ __launch_bounds__(256) void transpose_to_bf16(const T* __restrict__ src,
                                                         ushort* __restrict__ dst,
                                                         int R, int C, int srcLd,
                                                         long long ss, long long ds) {
    __shared__ float tile[32][33];
    src += (long long)blockIdx.z * ss;
    dst += (long long)blockIdx.z * ds;
    const int c0 = blockIdx.x * 32;
    const int r0 = blockIdx.y * 32;
    const int tx = threadIdx.x, ty = threadIdx.y;
#pragma unroll
    for (int i = 0; i < 4; i++) {
        int r = r0 + ty + i * 8;
        tile[ty + i * 8][tx] = to_f(src[(long long)r * srcLd + c0 + tx]);
    }
    __syncthreads();
#pragma unroll
    for (int i = 0; i < 4; i++) {
        int r = c0 + ty + i * 8;  // row of dst, in [0, C)
        dst[(long long)r * R + r0 + tx] = f2b(tile[tx][ty + i * 8]);
    }
}

// ---------------- bf16 MFMA GEMM:  C[M,N] = A[M,K] * BT[N,K]^T (+bias, relu, scale) ----
// 128x128 tile per 256-thread block (4 waves, each 64x64 = 4x4 MFMA 16x16x32 tiles).
// Staging via global_load_lds width=16 (m97 structure): UNPADDED LDS [row][32],
// wave w instr i covers rows w*32+i*16..+16; lane l -> row +(l>>2), col (l&3)*8.
// Grid: (N/128, M/128, batch*kChunks). gridDim.y must be a multiple of 8 (XCD swizzle).
// Split-K (kChunks>1): blockIdx.z = batch*kChunks + kIdx; chunk kIdx writes its
// partial (plain coalesced stores, NO atomics) at C + kIdx*sK; bias on chunk 0 only.
// Reduction of partials is fused into the downstream residual_ln.

#define BM 128
#define BN 128
#define BKK 32

template <int OUT_BF16, int RELU, int HAS_BIAS>
__global__ __launch_bounds__(256) void gemm_bt(const ushort* __restrict__ A,
                                               const ushort* __restrict__ BT,
                                               void* __restrict__ Cp,
                                               const float* __restrict__ bias,
                                               int N, int K, int kChunks, float scale,
                                               int lda, int ldb, int ldc,
                                               long long sA, long long sB, long long sC,
                                               long long sK) {
    __shared__ ushort As[BM * BKK];
    __shared__ ushort Bs[BN * BKK];

    const int tid = threadIdx.x;
    const int kIdx = blockIdx.z % kChunks;
    const int bz = blockIdx.z / kChunks;
    const int kLen = K / kChunks;
    const int kOff = kIdx * kLen;
    const ushort* Ab = A + (long long)bz * sA;
    const ushort* Bb = BT + (long long)bz * sB;

    // XCD-panel swizzle: blocks with the same (linear id % 8) -> same XCD (heuristic).
    // Each XCD gets a contiguous Hp-row panel iterated column-major for B-tile reuse.
    // R3 evidence: FETCH 269 MB -> 74 MB on FFN2. Keep.
    const int W = gridDim.x, H = gridDim.y;
    const int b = blockIdx.y * W + blockIdx.x;
    const int Hp = H >> 3;
    const int xcd = b & 7;
    const int s = b >> 3;
    const int tn = s / Hp;
    const int tm = xcd * Hp + (s % Hp);

    const int lane = tid & 63;
    const int wave = tid >> 6;
    const int wm = (wave >> 1) * 64;
    const int wn = (wave & 1) * 64;
    const int quad = lane >> 4;
    const int l16 = lane & 15;

    // async staging addresses: wave covers rows [wave*32, wave*32+32)
    const int srow = wave * 32 + (lane >> 2);  // instr 1 adds 16 rows
    const int scol = (lane & 3) * 8;
    const ushort* AgL = Ab + (long long)(tm * BM + srow) * lda + scol + kOff;
    const ushort* BgL = Bb + (long long)(tn * BN + srow) * ldb + scol + kOff;
    ushort* AsL = As + wave * 1024;  // wave*2048 bytes; instr 1 adds 512 elems
    ushort* BsL = Bs + wave * 1024;
    const long long rstepA = (long long)16 * lda;
    const long long rstepB = (long long)16 * ldb;

    f32x4 acc[4][4];
#pragma unroll
    for (int i = 0; i < 4; i++)
#pragma unroll
        for (int j = 0; j < 4; j++) acc[i][j] = (f32x4){0.f, 0.f, 0.f, 0.f};

    for (int k0 = 0; k0 < kLen; k0 += BKK) {
        async_ld16(AgL + k0, AsL);
        async_ld16(AgL + rstepA + k0, AsL + 512);
        async_ld16(BgL + k0, BsL);
        async_ld16(BgL + rstepB + k0, BsL + 512);
        __syncthreads();  // compiler emits s_waitcnt vmcnt(0) before s_barrier

        s16x8 af[4], bf[4];
#pragma unroll
        for (int i = 0; i < 4; i++)
            af[i] = *(const s16x8*)&As[(wm + i * 16 + l16) * BKK + quad * 8];
#pragma unroll
        for (int j = 0; j < 4; j++)
            bf[j] = *(const s16x8*)&Bs[(wn + j * 16 + l16) * BKK + quad * 8];
#pragma unroll
        for (int i = 0; i < 4; i++)
#pragma unroll
            for (int j = 0; j < 4; j++)
                acc[i][j] = __builtin_amdgcn_mfma_f32_16x16x32_bf16(af[i], bf[j], acc[i][j], 0, 0, 0);
        __syncthreads();
    }

    // epilogue: C/D layout col = lane&15, row = quad*4 + reg  [verified m89/m91]
    const long long cb = (long long)bz * sC + (long long)kIdx * sK;
    float* Cf = (float*)Cp;
    ushort* Cb = (ushort*)Cp;
#pragma unroll
    for (int j = 0; j < 4; j++) {
        const int col = tn * BN + wn + j * 16 + l16;
        float bv = (HAS_BIAS && kIdx == 0) ? bias[col] : 0.0f;
#pragma unroll
        for (int i = 0; i < 4; i++) {
            const int row0 = tm * BM + wm + i * 16 + quad * 4;
#pragma unroll
            for (int r = 0; r < 4; r++) {
                float v = acc[i][j][r] * scale + bv;
                if (RELU) v = v > 0.f ? v : 0.f;
                long long idx = cb + (long long)(row0 + r) * ldc + col;
                if (OUT_BF16) Cb[idx] = f2b(v);
                else Cf[idx] = v;
            }
        }
    }
}

// ---------------- row softmax: fp32 [rows][2048] -> bf16 ----------------

__global__ __launch_bounds__(256) void softmax_rows(const float* __restrict__ S,
                                                    ushort* __restrict__ P) {
    const int C = 2048;
    const long long row = blockIdx.x;
    const float* s = S + row * C;
    ushort* p = P + row * C;
    const int tid = threadIdx.x;
    float v[8];
    float mx = -1e30f;
#pragma unroll
    for (int i = 0; i < 8; i++) {
        v[i] = s[tid + i * 256];
        mx = fmaxf(mx, v[i]);
    }
    __shared__ float red[256];
    red[tid] = mx;
    __syncthreads();
    for (int off = 128; off > 0; off >>= 1) {
        if (tid < off) red[tid] = fmaxf(red[tid], red[tid + off]);
        __syncthreads();
    }
    mx = red[0];
    __syncthreads();
    float sum = 0.f;
#pragma unroll
    for (int i = 0; i < 8; i++) {
        v[i] = __expf(v[i] - mx);
        sum += v[i];
    }
    red[tid] = sum;
    __syncthreads();
    for (int off = 128; off > 0; off >>= 1) {
        if (tid < off) red[tid] += red[tid + off];
        __syncthreads();
    }
    float inv = 1.f / red[0];
#pragma unroll
    for (int i = 0; i < 8; i++) p[tid + i * 256] = f2b(v[i] * inv);
}

// ---------------- fused residual(+partial-sum) + LayerNorm (D=1024) ----------------
// out = LN(X + Y + (Y2?)) ; Y2 nullable (split-K partial reduction fused here).

__global__ __launch_bounds__(256) void residual_ln(const float* __restrict__ X,
                                                   const float* __restrict__ Y,
                                                   const float* __restrict__ Y2,
                                                   const float* __restrict__ g,
                                                   const float* __restrict__ be,
                                                   float* __restrict__ outf,
                                                   ushort* __restrict__ outb) {
    const int D = 1024;
    const long long row = blockIdx.x;
    const float* x = X + row * D;
    const float* y = Y + row * D;
    const float* y2 = Y2 ? Y2 + row * D : nullptr;
    const int tid = threadIdx.x;
    float v[4];
    float s = 0.f, s2 = 0.f;
#pragma unroll
    for (int i = 0; i < 4; i++) {
        int c = tid + i * 256;
        float t = x[c] + y[c];
        if (y2) t += y2[c];
        v[i] = t;
        s += t;
        s2 += t * t;
    }
    __shared__ float r1[256], r2[256];
    r1[tid] = s;
    r2[tid] = s2;
    __syncthreads();
    for (int off = 128; off > 0; off >>= 1) {
        if (tid < off) {
            r1[tid] += r1[tid + off];
            r2[tid] += r2[tid + off];
        }
        __syncthreads();
    }
    float mu = r1[0] * (1.f / 1024.f);
    float var = r2[0] * (1.f / 1024.f) - mu * mu;
    float inv = rsqrtf(var + 1e-5f);
    float* of = outf + row * D;
    ushort* ob = outb ? outb + row * D : nullptr;
#pragma unroll
    for (int i = 0; i < 4; i++) {
        int c = tid + i * 256;
        float o = (v[i] - mu) * inv * g[c] + be[c];
        of[c] = o;
        if (ob) ob[c] = f2b(o);
    }
}

// ---------------- launch ----------------

extern "C" void kernel_launch(void* const* d_in, const int* in_sizes, int n_in,
                              void* d_out, int out_size, void* d_ws, size_t ws_size,
                              hipStream_t stream) {
    const float* x  = (const float*)d_in[0];
    const float* wq = (const float*)d_in[1];
    const float* bq = (const float*)d_in[2];
    const float* wk = (const float*)d_in[3];
    const float* bk = (const float*)d_in[4];
    const float* wv = (const float*)d_in[5];
    const float* bv = (const float*)d_in[6];
    const float* wo = (const float*)d_in[7];
    const float* bo = (const float*)d_in[8];
    const float* w1 = (const float*)d_in[9];
    const float* b1 = (const float*)d_in[10];
    const float* w2 = (const float*)d_in[11];
    const float* b2 = (const float*)d_in[12];
    const float* g1 = (const float*)d_in[13];
    const float* be1 = (const float*)d_in[14];
    const float* g2 = (const float*)d_in[15];
    const float* be2 = (const float*)d_in[16];
    float* out = (float*)d_out;
    char* ws = (char*)d_ws;

    const int Bz = 4, S = 2048, D = 1024, F = 4096;
    const int T = Bz * S;  // 8192 rows
    const size_t MBy = 1024ull * 1024ull;

    // workspace layout (byte offsets), lifetime-based reuse; peak 200 MB
    ushort* qkvT = (ushort*)(ws + 0);        // 6 MB   [3072][1024] fused wq/wk/wv^T
    ushort* woT  = (ushort*)(ws + 6 * MBy);  // 2 MB
    ushort* w1T  = (ushort*)(ws + 8 * MBy);  // 8 MB   [F][D]
    ushort* w2T  = (ushort*)(ws + 16 * MBy); // 8 MB   [D][F]
    float*  bqkv = (float*)(ws + 24 * MBy);  // 12 KB  (dead after QKV gemm)
    ushort* xb   = (ushort*)(ws + 25 * MBy); // 16 MB  (dead after QKV gemm)
    ushort* qkv  = (ushort*)(ws + 41 * MBy); // 48 MB  [T][3072] (dead after scores+vT)
    ushort* vT   = (ushort*)(ws + 89 * MBy); // 16 MB  [B][D][S] (dead after ctx)
    float*  sc   = (float*)(ws + 105 * MBy); // 64 MB  scores fp32 (dead after softmax)
    ushort* attn = (ushort*)(ws + 169 * MBy); // 32 MB (dead after ctx)
    // reuse (non-overlapping lifetimes):
    ushort* ctx = (ushort*)(ws + 25 * MBy);  // 16 MB over xb/bqkv (dead after wo)
    float*  ao  = (float*)(ws + 105 * MBy);  // 32 MB over sc (dead after ln1)
    float*  x1  = (float*)(ws + 41 * MBy);   // 32 MB over qkv (live to ln2)
    ushort* x1b = (ushort*)(ws + 73 * MBy);  // 16 MB over qkv (dead after ffn1)
    ushort* h   = (ushort*)(ws + 105 * MBy); // 64 MB over sc/ao (after ln1)
    float*  ff0 = (float*)(ws + 169 * MBy);  // 32 MB over attn
    float*  ff1 = (float*)(ws + 73 * MBy);   // 32 MB over x1b+vT (both dead by ffn2)

    dim3 b32(32, 8);

    // 1) cast x -> bf16
    cast_f2b4<<<(T * D) / 1024, 256, 0, stream>>>(x, xb, (long long)(T * D) / 4);

    // 2) transpose-cast weights: wq/wk/wv stacked into qkvT [3072][1024]
    transpose_to_bf16<float><<<dim3(32, 32, 1), b32, 0, stream>>>(wq, qkvT, D, D, D, 0, 0);
    transpose_to_bf16<float><<<dim3(32, 32, 1), b32, 0, stream>>>(wk, qkvT + 1024 * 1024, D, D, D, 0, 0);
    transpose_to_bf16<float><<<dim3(32, 32, 1), b32, 0, stream>>>(wv, qkvT + 2048 * 1024, D, D, D, 0, 0);
    transpose_to_bf16<float><<<dim3(32, 32, 1), b32, 0, stream>>>(wo, woT, D, D, D, 0, 0);
    transpose_to_bf16<float><<<dim3(128, 32, 1), b32, 0, stream>>>(w1, w1T, D, F, F, 0, 0);
    transpose_to_bf16<float><<<dim3(32, 128, 1), b32, 0, stream>>>(w2, w2T, F, D, D, 0, 0);

    // 3) fused bias vector [bq|bk|bv]
    hipMemcpyAsync(bqkv, bq, D * sizeof(float), hipMemcpyDeviceToDevice, stream);
    hipMemcpyAsync(bqkv + D, bk, D * sizeof(float), hipMemcpyDeviceToDevice, stream);
    hipMemcpyAsync(bqkv + 2 * D, bv, D * sizeof(float), hipMemcpyDeviceToDevice, stream);

    // 4) fused QKV projection: [T][1024] x [3072][1024]^T -> [T][3072] bf16 (1536 blocks)
    gemm_bt<1, 0, 1><<<dim3(3 * D / 128, T / 128, 1), 256, 0, stream>>>(
        xb, qkvT, qkv, bqkv, 3 * D, D, 1, 1.f, D, D, 3 * D, 0, 0, 0, 0);

    // 5) V^T per batch: qkv v-slice [S][1024] (ld 3072) -> [D][S]
    transpose_to_bf16<ushort><<<dim3(D / 32, S / 32, Bz), b32, 0, stream>>>(
        qkv + 2048, vT, S, D, 3 * D, (long long)S * 3 * D, (long long)S * D);

    // 6) scores = Q K^T / 32 (fp32); A=q, B=k slices of qkv (ld 3072)
    gemm_bt<0, 0, 0><<<dim3(S / 128, S / 128, Bz), 256, 0, stream>>>(
        qkv, qkv + 1024, sc, nullptr, S, D, 1, 0.03125f, 3 * D, 3 * D, S,
        (long long)S * 3 * D, (long long)S * 3 * D, (long long)S * S, 0);

    // 7) softmax rows -> bf16 attn
    softmax_rows<<<T, 256, 0, stream>>>(sc, attn);

    // 8) ctx = attn @ V  (BT = V^T [D][S]) -> bf16 [S][D] per batch
    gemm_bt<1, 0, 0><<<dim3(D / 128, S / 128, Bz), 256, 0, stream>>>(
        attn, vT, ctx, nullptr, D, S, 1, 1.f, S, S, D,
        (long long)S * S, (long long)D * S, (long long)S * D, 0);

    // 9) attn_out = ctx @ wo^T + bo (fp32, non-split; 512 blocks w/ swizzle)
    gemm_bt<0, 0, 1><<<dim3(D / 128, T / 128, 1), 256, 0, stream>>>(
        ctx, woT, ao, bo, D, D, 1, 1.f, D, D, D, 0, 0, 0, 0);

    // 10) x1 = LN(x + ao) -> fp32 + bf16
    residual_ln<<<T, 256, 0, stream>>>(x, ao, nullptr, g1, be1, x1, x1b);

    // 11) h = relu(x1 @ w1 + b1) (bf16, 2048 blocks)
    gemm_bt<1, 1, 1><<<dim3(F / 128, T / 128, 1), 256, 0, stream>>>(
        x1b, w1T, h, b1, F, D, 1, 1.f, D, D, F, 0, 0, 0, 0);

    // 12) ff partials = h @ w2 (+b2 on chunk 0), split-K=2, plain stores (1024 blocks)
    //     chunk 0 -> ff0, chunk 1 -> ff1 = ff0 + sK (negative offset into reused region)
    gemm_bt<0, 0, 1><<<dim3(D / 128, T / 128, 2), 256, 0, stream>>>(
        h, w2T, ff0, b2, D, F, 2, 1.f, F, F, D, 0, 0, 0, (long long)(ff1 - ff0));

    // 13) out = LN(x1 + ff0 + ff1) -> d_out fp32 (split-K reduction fused)
    residual_ln<<<T, 256, 0, stream>>>(x1, ff0, ff1, g2, be2, out, nullptr);
}

// Round 5
// 630.516 us; speedup vs baseline: 1.1873x; 1.0485x over previous
//
#include <hip/hip_runtime.h>
#include <stdint.h>

// ---------------- common helpers ----------------

using f32x4 = __attribute__((ext_vector_type(4))) float;
using s16x8 = __attribute__((ext_vector_type(8))) short;

__device__ __forceinline__ ushort f2b(float f) {
    union { float f; uint32_t u; } v; v.f = f;
    uint32_t u = v.u;
    return (ushort)((u + 0x7fffu + ((u >> 16) & 1u)) >> 16);
}
__device__ __forceinline__ float b2f(ushort b) {
    union { uint32_t u; float f; } v; v.u = ((uint32_t)b) << 16;
    return v.f;
}
__device__ __forceinline__ float to_f(float f) { return f; }
__device__ __forceinline__ float to_f(ushort b) { return b2f(b); }

// async global->LDS, 16B per lane; LDS dest = wave-uniform base + lane*16
__device__ __forceinline__ void async_ld16(const ushort* g, ushort* l) {
    __builtin_amdgcn_global_load_lds(
        (const __attribute__((address_space(1))) void*)g,
        (__attribute__((address_space(3))) void*)l,
        16, 0, 0);
}

// s_waitcnt immediates (gfx9 encoding): vmcnt[3:0]|[15:14], expcnt[6:4], lgkmcnt[11:8]
#define WAITCNT_VM4 0x0F74  // vmcnt=4, lgkm/exp no-wait
#define WAITCNT_VM0 0x0F70  // vmcnt=0, lgkm/exp no-wait

// ---------------- cast fp32 -> bf16 (vectorized x4) ----------------

__global__ __launch_bounds__(256) void cast_f2b4(const float* __restrict__ src,
                                                 ushort* __restrict__ dst,
                                                 long long n4) {
    long long i = (long long)blockIdx.x * 256 + threadIdx.x;
    if (i >= n4) return;
    float4 f = ((const float4*)src)[i];
    ushort4 o;
    o.x = f2b(f.x); o.y = f2b(f.y); o.z = f2b(f.z); o.w = f2b(f.w);
    ((ushort4*)dst)[i] = o;
}

// ---------------- transpose (fp32 or bf16 in) -> bf16 out ----------------
// src: [R][C] with row stride srcLd, dst: [C][R] row-major.
// Grid: (C/32, R/32, batch), block (32,8).

template <typename T>
__global__ __launch_bounds__(256) void transpose_to_bf16(const T* __restrict__ src,
                                                         ushort* __restrict__ dst,
                                                         int R, int C, int srcLd,
                                                         long long ss, long long ds) {
    __shared__ float tile[32][33];
    src += (long long)blockIdx.z * ss;
    dst += (long long)blockIdx.z * ds;
    const int c0 = blockIdx.x * 32;
    const int r0 = blockIdx.y * 32;
    const int tx = threadIdx.x, ty = threadIdx.y;
#pragma unroll
    for (int i = 0; i < 4; i++) {
        int r = r0 + ty + i * 8;
        tile[ty + i * 8][tx] = to_f(src[(long long)r * srcLd + c0 + tx]);
    }
    __syncthreads();
#pragma unroll
    for (int i = 0; i < 4; i++) {
        int r = c0 + ty + i * 8;  // row of dst, in [0, C)
        dst[(long long)r * R + r0 + tx] = f2b(tile[tx][ty + i * 8]);
    }
}

// ---------------- bf16 MFMA GEMM:  C[M,N] = A[M,K] * BT[N,K]^T (+bias, relu, scale) ----
// 128x128 tile per 256-thread block (4 waves, each 64x64 = 4x4 MFMA 16x16x32 tiles).
// Staging via global_load_lds width=16: UNPADDED LDS [row][32], wave w instr i covers
// rows w*32+i*16..+16; lane l -> row +(l>>2), col (l&3)*8.
// PIPELINED K-loop (R5): double-buffered LDS; tile k+1 DMA issued before waiting tile k
// with s_waitcnt vmcnt(4) + raw s_barrier (loads stay in flight across the barrier).
// Grid: (N/128, M/128, batch*kChunks). gridDim.y must be a multiple of 8 (XCD swizzle).
// Split-K (kChunks>1): chunk kIdx writes its partial (plain stores, NO atomics) at
// C + kIdx*sK; bias on chunk 0 only; reduction fused into downstream residual_ln.

#define BM 128
#define BN 128
#define BKK 32
#define TILE_ELEMS (BM * BKK)  // 4096

template <int OUT_BF16, int RELU, int HAS_BIAS>
__global__ __launch_bounds__(256) void gemm_bt(const ushort* __restrict__ A,
                                               const ushort* __restrict__ BT,
                                               void* __restrict__ Cp,
                                               const float* __restrict__ bias,
                                               int N, int K, int kChunks, float scale,
                                               int lda, int ldb, int ldc,
                                               long long sA, long long sB, long long sC,
                                               long long sK) {
    __shared__ ushort As[2 * TILE_ELEMS];
    __shared__ ushort Bs[2 * TILE_ELEMS];

    const int tid = threadIdx.x;
    const int kIdx = blockIdx.z % kChunks;
    const int bz = blockIdx.z / kChunks;
    const int kLen = K / kChunks;
    const int kOff = kIdx * kLen;
    const ushort* Ab = A + (long long)bz * sA;
    const ushort* Bb = BT + (long long)bz * sB;

    // XCD-panel swizzle (R3 evidence: FETCH 269->74 MB on FFN2). Keep.
    const int W = gridDim.x, H = gridDim.y;
    const int b = blockIdx.y * W + blockIdx.x;
    const int Hp = H >> 3;
    const int xcd = b & 7;
    const int s = b >> 3;
    const int tn = s / Hp;
    const int tm = xcd * Hp + (s % Hp);

    const int lane = tid & 63;
    const int wave = tid >> 6;
    const int wm = (wave >> 1) * 64;
    const int wn = (wave & 1) * 64;
    const int quad = lane >> 4;
    const int l16 = lane & 15;

    // async staging addresses: wave covers rows [wave*32, wave*32+32)
    const int srow = wave * 32 + (lane >> 2);  // instr 1 adds 16 rows
    const int scol = (lane & 3) * 8;
    const ushort* AgL = Ab + (long long)(tm * BM + srow) * lda + scol + kOff;
    const ushort* BgL = Bb + (long long)(tn * BN + srow) * ldb + scol + kOff;
    ushort* AsL = As + wave * 1024;  // per-buffer wave base; instr 1 adds 512 elems
    ushort* BsL = Bs + wave * 1024;
    const long long rstepA = (long long)16 * lda;
    const long long rstepB = (long long)16 * ldb;

    f32x4 acc[4][4];
#pragma unroll
    for (int i = 0; i < 4; i++)
#pragma unroll
        for (int j = 0; j < 4; j++) acc[i][j] = (f32x4){0.f, 0.f, 0.f, 0.f};

    // prologue: issue tile 0 into buffer 0
    {
        async_ld16(AgL, AsL);
        async_ld16(AgL + rstepA, AsL + 512);
        async_ld16(BgL, BsL);
        async_ld16(BgL + rstepB, BsL + 512);
    }

    int p = 0;
    for (int k0 = 0; k0 < kLen; k0 += BKK) {
        // issue tile k+1 into alternate buffer, then wait only for tile k (4 oldest)
        if (k0 + BKK < kLen) {
            const int q = p ^ 1;
            async_ld16(AgL + (k0 + BKK), AsL + q * TILE_ELEMS);
            async_ld16(AgL + rstepA + (k0 + BKK), AsL + q * TILE_ELEMS + 512);
            async_ld16(BgL + (k0 + BKK), BsL + q * TILE_ELEMS);
            async_ld16(BgL + rstepB + (k0 + BKK), BsL + q * TILE_ELEMS + 512);
            __builtin_amdgcn_s_waitcnt(WAITCNT_VM4);
        } else {
            __builtin_amdgcn_s_waitcnt(WAITCNT_VM0);
        }
        __builtin_amdgcn_s_barrier();  // all waves' tile-k DMA landed; k+1 stays in flight

        const ushort* Asp = As + p * TILE_ELEMS;
        const ushort* Bsp = Bs + p * TILE_ELEMS;
        s16x8 af[4], bf[4];
#pragma unroll
        for (int i = 0; i < 4; i++)
            af[i] = *(const s16x8*)&Asp[(wm + i * 16 + l16) * BKK + quad * 8];
#pragma unroll
        for (int j = 0; j < 4; j++)
            bf[j] = *(const s16x8*)&Bsp[(wn + j * 16 + l16) * BKK + quad * 8];
#pragma unroll
        for (int i = 0; i < 4; i++)
#pragma unroll
            for (int j = 0; j < 4; j++)
                acc[i][j] = __builtin_amdgcn_mfma_f32_16x16x32_bf16(af[i], bf[j], acc[i][j], 0, 0, 0);

        __builtin_amdgcn_s_barrier();  // everyone done reading buf p -> next iter may DMA it
        p ^= 1;
    }

    // epilogue: C/D layout col = lane&15, row = quad*4 + reg  [verified m89/m91]
    const long long cb = (long long)bz * sC + (long long)kIdx * sK;
    float* Cf = (float*)Cp;
    ushort* Cb = (ushort*)Cp;
#pragma unroll
    for (int j = 0; j < 4; j++) {
        const int col = tn * BN + wn + j * 16 + l16;
        float bv = (HAS_BIAS && kIdx == 0) ? bias[col] : 0.0f;
#pragma unroll
        for (int i = 0; i < 4; i++) {
            const int row0 = tm * BM + wm + i * 16 + quad * 4;
#pragma unroll
            for (int r = 0; r < 4; r++) {
                float v = acc[i][j][r] * scale + bv;
                if (RELU) v = v > 0.f ? v : 0.f;
                long long idx = cb + (long long)(row0 + r) * ldc + col;
                if (OUT_BF16) Cb[idx] = f2b(v);
                else Cf[idx] = v;
            }
        }
    }
}

// ---------------- row softmax: bf16 [rows][2048] -> bf16, vectorized 8/thread -------

__global__ __launch_bounds__(256) void softmax_rows(const ushort* __restrict__ S,
                                                    ushort* __restrict__ P) {
    const int C = 2048;
    const long long row = blockIdx.x;
    const int tid = threadIdx.x;
    const ushort4* s4 = (const ushort4*)(S + row * C) + tid * 2;  // 8 contiguous elems
    ushort4 a = s4[0], bq = s4[1];
    float v[8];
    v[0] = b2f(a.x); v[1] = b2f(a.y); v[2] = b2f(a.z); v[3] = b2f(a.w);
    v[4] = b2f(bq.x); v[5] = b2f(bq.y); v[6] = b2f(bq.z); v[7] = b2f(bq.w);
    float mx = -1e30f;
#pragma unroll
    for (int i = 0; i < 8; i++) mx = fmaxf(mx, v[i]);
    __shared__ float red[256];
    red[tid] = mx;
    __syncthreads();
    for (int off = 128; off > 0; off >>= 1) {
        if (tid < off) red[tid] = fmaxf(red[tid], red[tid + off]);
        __syncthreads();
    }
    mx = red[0];
    __syncthreads();
    float sum = 0.f;
#pragma unroll
    for (int i = 0; i < 8; i++) {
        v[i] = __expf(v[i] - mx);
        sum += v[i];
    }
    red[tid] = sum;
    __syncthreads();
    for (int off = 128; off > 0; off >>= 1) {
        if (tid < off) red[tid] += red[tid + off];
        __syncthreads();
    }
    float inv = 1.f / red[0];
    ushort4 o0, o1;
    o0.x = f2b(v[0] * inv); o0.y = f2b(v[1] * inv); o0.z = f2b(v[2] * inv); o0.w = f2b(v[3] * inv);
    o1.x = f2b(v[4] * inv); o1.y = f2b(v[5] * inv); o1.z = f2b(v[6] * inv); o1.w = f2b(v[7] * inv);
    ushort4* p4 = (ushort4*)(P + row * C) + tid * 2;
    p4[0] = o0;
    p4[1] = o1;
}

// ---------------- fused residual(+partial-sum) + LayerNorm (D=1024) ----------------
// out = LN(X + Y + (Y2?)) ; Y2 nullable (split-K partial reduction fused here).

__global__ __launch_bounds__(256) void residual_ln(const float* __restrict__ X,
                                                   const float* __restrict__ Y,
                                                   const float* __restrict__ Y2,
                                                   const float* __restrict__ g,
                                                   const float* __restrict__ be,
                                                   float* __restrict__ outf,
                                                   ushort* __restrict__ outb) {
    const int D = 1024;
    const long long row = blockIdx.x;
    const float* x = X + row * D;
    const float* y = Y + row * D;
    const float* y2 = Y2 ? Y2 + row * D : nullptr;
    const int tid = threadIdx.x;
    float v[4];
    float s = 0.f, s2 = 0.f;
#pragma unroll
    for (int i = 0; i < 4; i++) {
        int c = tid + i * 256;
        float t = x[c] + y[c];
        if (y2) t += y2[c];
        v[i] = t;
        s += t;
        s2 += t * t;
    }
    __shared__ float r1[256], r2[256];
    r1[tid] = s;
    r2[tid] = s2;
    __syncthreads();
    for (int off = 128; off > 0; off >>= 1) {
        if (tid < off) {
            r1[tid] += r1[tid + off];
            r2[tid] += r2[tid + off];
        }
        __syncthreads();
    }
    float mu = r1[0] * (1.f / 1024.f);
    float var = r2[0] * (1.f / 1024.f) - mu * mu;
    float inv = rsqrtf(var + 1e-5f);
    float* of = outf + row * D;
    ushort* ob = outb ? outb + row * D : nullptr;
#pragma unroll
    for (int i = 0; i < 4; i++) {
        int c = tid + i * 256;
        float o = (v[i] - mu) * inv * g[c] + be[c];
        of[c] = o;
        if (ob) ob[c] = f2b(o);
    }
}

// ---------------- launch ----------------

extern "C" void kernel_launch(void* const* d_in, const int* in_sizes, int n_in,
                              void* d_out, int out_size, void* d_ws, size_t ws_size,
                              hipStream_t stream) {
    const float* x  = (const float*)d_in[0];
    const float* wq = (const float*)d_in[1];
    const float* bq = (const float*)d_in[2];
    const float* wk = (const float*)d_in[3];
    const float* bk = (const float*)d_in[4];
    const float* wv = (const float*)d_in[5];
    const float* bv = (const float*)d_in[6];
    const float* wo = (const float*)d_in[7];
    const float* bo = (const float*)d_in[8];
    const float* w1 = (const float*)d_in[9];
    const float* b1 = (const float*)d_in[10];
    const float* w2 = (const float*)d_in[11];
    const float* b2 = (const float*)d_in[12];
    const float* g1 = (const float*)d_in[13];
    const float* be1 = (const float*)d_in[14];
    const float* g2 = (const float*)d_in[15];
    const float* be2 = (const float*)d_in[16];
    float* out = (float*)d_out;
    char* ws = (char*)d_ws;

    const int Bz = 4, S = 2048, D = 1024, F = 4096;
    const int T = Bz * S;  // 8192 rows
    const size_t MBy = 1024ull * 1024ull;

    // workspace layout (byte offsets), lifetime-based reuse; peak 201 MB
    ushort* qkvT = (ushort*)(ws + 0);        // 6 MB   [3072][1024] fused wq/wk/wv^T
    ushort* woT  = (ushort*)(ws + 6 * MBy);  // 2 MB
    ushort* w1T  = (ushort*)(ws + 8 * MBy);  // 8 MB   [F][D]
    ushort* w2T  = (ushort*)(ws + 16 * MBy); // 8 MB   [D][F]
    float*  bqkv = (float*)(ws + 24 * MBy);  // 12 KB  (dead after QKV gemm)
    ushort* xb   = (ushort*)(ws + 25 * MBy); // 16 MB  (dead after QKV gemm)
    ushort* qkv  = (ushort*)(ws + 41 * MBy); // 48 MB  [T][3072] (dead after scores+vT)
    ushort* vT   = (ushort*)(ws + 89 * MBy); // 16 MB  [B][D][S] (dead after ctx)
    ushort* scb  = (ushort*)(ws + 105 * MBy); // 32 MB bf16 scores (dead after softmax)
    ushort* attn = (ushort*)(ws + 169 * MBy); // 32 MB (dead after ctx)
    // reuse (non-overlapping lifetimes):
    ushort* ctx = (ushort*)(ws + 25 * MBy);  // 16 MB over xb/bqkv (dead after wo)
    float*  ao0 = (float*)(ws + 105 * MBy);  // 32 MB over scb (dead after ln1)
    float*  ao1 = (float*)(ws + 137 * MBy);  // 32 MB (dead after ln1)
    float*  x1  = (float*)(ws + 41 * MBy);   // 32 MB over qkv (live to ln2)
    ushort* x1b = (ushort*)(ws + 73 * MBy);  // 16 MB over qkv (dead after ffn1)
    ushort* h   = (ushort*)(ws + 105 * MBy); // 64 MB over scb/ao (after ln1)
    float*  ff0 = (float*)(ws + 169 * MBy);  // 32 MB over attn
    float*  ff1 = (float*)(ws + 73 * MBy);   // 32 MB over x1b+vT (both dead by ffn2)

    dim3 b32(32, 8);

    // 1) cast x -> bf16
    cast_f2b4<<<(T * D) / 1024, 256, 0, stream>>>(x, xb, (long long)(T * D) / 4);

    // 2) transpose-cast weights: wq/wk/wv stacked into qkvT [3072][1024]
    transpose_to_bf16<float><<<dim3(32, 32, 1), b32, 0, stream>>>(wq, qkvT, D, D, D, 0, 0);
    transpose_to_bf16<float><<<dim3(32, 32, 1), b32, 0, stream>>>(wk, qkvT + 1024 * 1024, D, D, D, 0, 0);
    transpose_to_bf16<float><<<dim3(32, 32, 1), b32, 0, stream>>>(wv, qkvT + 2048 * 1024, D, D, D, 0, 0);
    transpose_to_bf16<float><<<dim3(32, 32, 1), b32, 0, stream>>>(wo, woT, D, D, D, 0, 0);
    transpose_to_bf16<float><<<dim3(128, 32, 1), b32, 0, stream>>>(w1, w1T, D, F, F, 0, 0);
    transpose_to_bf16<float><<<dim3(32, 128, 1), b32, 0, stream>>>(w2, w2T, F, D, D, 0, 0);

    // 3) fused bias vector [bq|bk|bv]
    hipMemcpyAsync(bqkv, bq, D * sizeof(float), hipMemcpyDeviceToDevice, stream);
    hipMemcpyAsync(bqkv + D, bk, D * sizeof(float), hipMemcpyDeviceToDevice, stream);
    hipMemcpyAsync(bqkv + 2 * D, bv, D * sizeof(float), hipMemcpyDeviceToDevice, stream);

    // 4) fused QKV projection: [T][1024] x [3072][1024]^T -> [T][3072] bf16 (1536 blocks)
    gemm_bt<1, 0, 1><<<dim3(3 * D / 128, T / 128, 1), 256, 0, stream>>>(
        xb, qkvT, qkv, bqkv, 3 * D, D, 1, 1.f, D, D, 3 * D, 0, 0, 0, 0);

    // 5) V^T per batch: qkv v-slice [S][1024] (ld 3072) -> [D][S]
    transpose_to_bf16<ushort><<<dim3(D / 32, S / 32, Bz), b32, 0, stream>>>(
        qkv + 2048, vT, S, D, 3 * D, (long long)S * 3 * D, (long long)S * D);

    // 6) scores = Q K^T / 32 -> bf16; A=q, B=k slices of qkv (ld 3072)
    gemm_bt<1, 0, 0><<<dim3(S / 128, S / 128, Bz), 256, 0, stream>>>(
        qkv, qkv + 1024, scb, nullptr, S, D, 1, 0.03125f, 3 * D, 3 * D, S,
        (long long)S * 3 * D, (long long)S * 3 * D, (long long)S * S, 0);

    // 7) softmax rows -> bf16 attn
    softmax_rows<<<T, 256, 0, stream>>>(scb, attn);

    // 8) ctx = attn @ V  (BT = V^T [D][S]) -> bf16 [S][D] per batch
    gemm_bt<1, 0, 0><<<dim3(D / 128, S / 128, Bz), 256, 0, stream>>>(
        attn, vT, ctx, nullptr, D, S, 1, 1.f, S, S, D,
        (long long)S * S, (long long)D * S, (long long)S * D, 0);

    // 9) attn_out partials = ctx @ wo^T (+bo chunk 0), split-K=2, plain stores (1024 blocks)
    gemm_bt<0, 0, 1><<<dim3(D / 128, T / 128, 2), 256, 0, stream>>>(
        ctx, woT, ao0, bo, D, D, 2, 1.f, D, D, D, 0, 0, 0, (long long)(ao1 - ao0));

    // 10) x1 = LN(x + ao0 + ao1) -> fp32 + bf16 (split-K reduction fused)
    residual_ln<<<T, 256, 0, stream>>>(x, ao0, ao1, g1, be1, x1, x1b);

    // 11) h = relu(x1 @ w1 + b1) (bf16, 2048 blocks)
    gemm_bt<1, 1, 1><<<dim3(F / 128, T / 128, 1), 256, 0, stream>>>(
        x1b, w1T, h, b1, F, D, 1, 1.f, D, D, F, 0, 0, 0, 0);

    // 12) ff partials = h @ w2 (+b2 on chunk 0), split-K=2, plain stores (1024 blocks)
    gemm_bt<0, 0, 1><<<dim3(D / 128, T / 128, 2), 256, 0, stream>>>(
        h, w2T, ff0, b2, D, F, 2, 1.f, F, F, D, 0, 0, 0, (long long)(ff1 - ff0));

    // 13) out = LN(x1 + ff0 + ff1) -> d_out fp32 (split-K reduction fused)
    residual_ln<<<T, 256, 0, stream>>>(x1, ff0, ff1, g2, be2, out, nullptr);
}

// Round 6
// 626.756 us; speedup vs baseline: 1.1944x; 1.0060x over previous
//
#include <hip/hip_runtime.h>
#include <stdint.h>

// ---------------- common helpers ----------------

using f32x4 = __attribute__((ext_vector_type(4))) float;
using s16x8 = __attribute__((ext_vector_type(8))) short;

__device__ __forceinline__ ushort f2b(float f) {
    union { float f; uint32_t u; } v; v.f = f;
    uint32_t u = v.u;
    return (ushort)((u + 0x7fffu + ((u >> 16) & 1u)) >> 16);
}
__device__ __forceinline__ float b2f(ushort b) {
    union { uint32_t u; float f; } v; v.u = ((uint32_t)b) << 16;
    return v.f;
}
__device__ __forceinline__ float to_f(float f) { return f; }
__device__ __forceinline__ float to_f(ushort b) { return b2f(b); }

// async global->LDS, 16B per lane; LDS dest = wave-uniform base + lane*16
__device__ __forceinline__ void async_ld16(const ushort* g, ushort* l) {
    __builtin_amdgcn_global_load_lds(
        (const __attribute__((address_space(1))) void*)g,
        (__attribute__((address_space(3))) void*)l,
        16, 0, 0);
}

// s_waitcnt immediates (gfx9 encoding): vmcnt[3:0]|[15:14], expcnt[6:4], lgkmcnt[11:8]
#define WAITCNT_VM8 0x0F78  // vmcnt=8, lgkm/exp no-wait
#define WAITCNT_VM4 0x0F74  // vmcnt=4
#define WAITCNT_VM0 0x0F70  // vmcnt=0

// ---------------- cast fp32 -> bf16 (vectorized x4) ----------------

__global__ __launch_bounds__(256) void cast_f2b4(const float* __restrict__ src,
                                                 ushort* __restrict__ dst,
                                                 long long n4) {
    long long i = (long long)blockIdx.x * 256 + threadIdx.x;
    if (i >= n4) return;
    float4 f = ((const float4*)src)[i];
    ushort4 o;
    o.x = f2b(f.x); o.y = f2b(f.y); o.z = f2b(f.z); o.w = f2b(f.w);
    ((ushort4*)dst)[i] = o;
}

// ---------------- transpose (fp32 or bf16 in) -> bf16 out ----------------
// src: [R][C] with row stride srcLd, dst: [C][R] row-major.
// Grid: (C/32, R/32, batch), block (32,8).

template <typename T>
__global__ __launch_bounds__(256) void transpose_to_bf16(const T* __restrict__ src,
                                                         ushort* __restrict__ dst,
                                                         int R, int C, int srcLd,
                                                         long long ss, long long ds) {
    __shared__ float tile[32][33];
    src += (long long)blockIdx.z * ss;
    dst += (long long)blockIdx.z * ds;
    const int c0 = blockIdx.x * 32;
    const int r0 = blockIdx.y * 32;
    const int tx = threadIdx.x, ty = threadIdx.y;
#pragma unroll
    for (int i = 0; i < 4; i++) {
        int r = r0 + ty + i * 8;
        tile[ty + i * 8][tx] = to_f(src[(long long)r * srcLd + c0 + tx]);
    }
    __syncthreads();
#pragma unroll
    for (int i = 0; i < 4; i++) {
        int r = c0 + ty + i * 8;  // row of dst, in [0, C)
        dst[(long long)r * R + r0 + tx] = f2b(tile[tx][ty + i * 8]);
    }
}

// ---------------- bf16 MFMA GEMM:  C[M,N] = A[M,K] * BT[N,K]^T (+bias, relu, scale) ----
// 128x128 tile per 256-thread block (4 waves, each 64x64 = 4x4 MFMA 16x16x32 tiles).
// Staging via global_load_lds width=16: UNPADDED LDS [row][32], wave w instr i covers
// rows w*32+i*16..+16; lane l -> row +(l>>2), col (l&3)*8.
// 3-STAGE pipeline (R6): triple-buffered LDS; at iter k issue tile k+2, then
// s_waitcnt vmcnt(8) waits only tile k — tiles k+1,k+2 stay in flight across the
// barrier (~2 iterations of latency slack, covers HBM-miss ~900cyc).
// Slot hazard: write slot (k+2)%3 == (k-1)%3, last read iter k-1, trailing barrier
// of k-1 precedes iter k's DMA issue in all waves -> safe.
// Grid: (N/128, M/128, batch*kChunks). gridDim.y must be a multiple of 8 (XCD swizzle).
// Split-K (kChunks>1): chunk kIdx writes partial (plain stores, NO atomics) at
// C + kIdx*sK; bias on chunk 0 only; reduction fused into downstream residual_ln.

#define BM 128
#define BN 128
#define BKK 32
#define TILE_ELEMS (BM * BKK)  // 4096

template <int OUT_BF16, int RELU, int HAS_BIAS>
__global__ __launch_bounds__(256) void gemm_bt(const ushort* __restrict__ A,
                                               const ushort* __restrict__ BT,
                                               void* __restrict__ Cp,
                                               const float* __restrict__ bias,
                                               int N, int K, int kChunks, float scale,
                                               int lda, int ldb, int ldc,
                                               long long sA, long long sB, long long sC,
                                               long long sK) {
    __shared__ ushort As[3 * TILE_ELEMS];  // 24 KB
    __shared__ ushort Bs[3 * TILE_ELEMS];  // 24 KB

    const int tid = threadIdx.x;
    const int kIdx = blockIdx.z % kChunks;
    const int bz = blockIdx.z / kChunks;
    const int kLen = K / kChunks;
    const int kOff = kIdx * kLen;
    const ushort* Ab = A + (long long)bz * sA;
    const ushort* Bb = BT + (long long)bz * sB;

    // XCD-panel swizzle (R3 evidence: FETCH 269->74 MB on FFN2). Keep.
    const int W = gridDim.x, H = gridDim.y;
    const int b = blockIdx.y * W + blockIdx.x;
    const int Hp = H >> 3;
    const int xcd = b & 7;
    const int s = b >> 3;
    const int tn = s / Hp;
    const int tm = xcd * Hp + (s % Hp);

    const int lane = tid & 63;
    const int wave = tid >> 6;
    const int wm = (wave >> 1) * 64;
    const int wn = (wave & 1) * 64;
    const int quad = lane >> 4;
    const int l16 = lane & 15;

    // async staging addresses: wave covers rows [wave*32, wave*32+32)
    const int srow = wave * 32 + (lane >> 2);  // instr 1 adds 16 rows
    const int scol = (lane & 3) * 8;
    const ushort* AgL = Ab + (long long)(tm * BM + srow) * lda + scol + kOff;
    const ushort* BgL = Bb + (long long)(tn * BN + srow) * ldb + scol + kOff;
    ushort* AsL = As + wave * 1024;  // per-buffer wave base; instr 1 adds 512 elems
    ushort* BsL = Bs + wave * 1024;
    const long long rstepA = (long long)16 * lda;
    const long long rstepB = (long long)16 * ldb;

    f32x4 acc[4][4];
#pragma unroll
    for (int i = 0; i < 4; i++)
#pragma unroll
        for (int j = 0; j < 4; j++) acc[i][j] = (f32x4){0.f, 0.f, 0.f, 0.f};

    const int nIter = kLen / BKK;

    // prologue: tile 0 -> slot 0; tile 1 -> slot 1
    async_ld16(AgL, AsL);
    async_ld16(AgL + rstepA, AsL + 512);
    async_ld16(BgL, BsL);
    async_ld16(BgL + rstepB, BsL + 512);
    if (nIter > 1) {
        async_ld16(AgL + BKK, AsL + TILE_ELEMS);
        async_ld16(AgL + rstepA + BKK, AsL + TILE_ELEMS + 512);
        async_ld16(BgL + BKK, BsL + TILE_ELEMS);
        async_ld16(BgL + rstepB + BKK, BsL + TILE_ELEMS + 512);
    }

    int cur = 0;   // slot of tile k
    int wsl = 2;   // slot of tile k+2
    for (int it = 0; it < nIter; it++) {
        if (it + 2 < nIter) {
            const int k2 = (it + 2) * BKK;
            async_ld16(AgL + k2, AsL + wsl * TILE_ELEMS);
            async_ld16(AgL + rstepA + k2, AsL + wsl * TILE_ELEMS + 512);
            async_ld16(BgL + k2, BsL + wsl * TILE_ELEMS);
            async_ld16(BgL + rstepB + k2, BsL + wsl * TILE_ELEMS + 512);
            __builtin_amdgcn_s_waitcnt(WAITCNT_VM8);  // only tile k must land
        } else if (it + 1 < nIter) {
            __builtin_amdgcn_s_waitcnt(WAITCNT_VM4);
        } else {
            __builtin_amdgcn_s_waitcnt(WAITCNT_VM0);
        }
        __builtin_amdgcn_s_barrier();  // tile k visible to all; k+1,k+2 in flight

        const ushort* Asp = As + cur * TILE_ELEMS;
        const ushort* Bsp = Bs + cur * TILE_ELEMS;
        s16x8 af[4], bf[4];
#pragma unroll
        for (int i = 0; i < 4; i++)
            af[i] = *(const s16x8*)&Asp[(wm + i * 16 + l16) * BKK + quad * 8];
#pragma unroll
        for (int j = 0; j < 4; j++)
            bf[j] = *(const s16x8*)&Bsp[(wn + j * 16 + l16) * BKK + quad * 8];
#pragma unroll
        for (int i = 0; i < 4; i++)
#pragma unroll
            for (int j = 0; j < 4; j++)
                acc[i][j] = __builtin_amdgcn_mfma_f32_16x16x32_bf16(af[i], bf[j], acc[i][j], 0, 0, 0);

        __builtin_amdgcn_s_barrier();  // all reads of slot cur done -> reusable next iter
        cur = cur + 1 == 3 ? 0 : cur + 1;
        wsl = wsl + 1 == 3 ? 0 : wsl + 1;
    }

    // epilogue: C/D layout col = lane&15, row = quad*4 + reg  [verified m89/m91]
    const long long cb = (long long)bz * sC + (long long)kIdx * sK;
    float* Cf = (float*)Cp;
    ushort* Cb = (ushort*)Cp;
#pragma unroll
    for (int j = 0; j < 4; j++) {
        const int col = tn * BN + wn + j * 16 + l16;
        float bv = (HAS_BIAS && kIdx == 0) ? bias[col] : 0.0f;
#pragma unroll
        for (int i = 0; i < 4; i++) {
            const int row0 = tm * BM + wm + i * 16 + quad * 4;
#pragma unroll
            for (int r = 0; r < 4; r++) {
                float v = acc[i][j][r] * scale + bv;
                if (RELU) v = v > 0.f ? v : 0.f;
                long long idx = cb + (long long)(row0 + r) * ldc + col;
                if (OUT_BF16) Cb[idx] = f2b(v);
                else Cf[idx] = v;
            }
        }
    }
}

// ---------------- row softmax: bf16 [rows][2048] -> bf16, vectorized 8/thread -------

__global__ __launch_bounds__(256) void softmax_rows(const ushort* __restrict__ S,
                                                    ushort* __restrict__ P) {
    const int C = 2048;
    const long long row = blockIdx.x;
    const int tid = threadIdx.x;
    const ushort4* s4 = (const ushort4*)(S + row * C) + tid * 2;  // 8 contiguous elems
    ushort4 a = s4[0], bq = s4[1];
    float v[8];
    v[0] = b2f(a.x); v[1] = b2f(a.y); v[2] = b2f(a.z); v[3] = b2f(a.w);
    v[4] = b2f(bq.x); v[5] = b2f(bq.y); v[6] = b2f(bq.z); v[7] = b2f(bq.w);
    float mx = -1e30f;
#pragma unroll
    for (int i = 0; i < 8; i++) mx = fmaxf(mx, v[i]);
    __shared__ float red[256];
    red[tid] = mx;
    __syncthreads();
    for (int off = 128; off > 0; off >>= 1) {
        if (tid < off) red[tid] = fmaxf(red[tid], red[tid + off]);
        __syncthreads();
    }
    mx = red[0];
    __syncthreads();
    float sum = 0.f;
#pragma unroll
    for (int i = 0; i < 8; i++) {
        v[i] = __expf(v[i] - mx);
        sum += v[i];
    }
    red[tid] = sum;
    __syncthreads();
    for (int off = 128; off > 0; off >>= 1) {
        if (tid < off) red[tid] += red[tid + off];
        __syncthreads();
    }
    float inv = 1.f / red[0];
    ushort4 o0, o1;
    o0.x = f2b(v[0] * inv); o0.y = f2b(v[1] * inv); o0.z = f2b(v[2] * inv); o0.w = f2b(v[3] * inv);
    o1.x = f2b(v[4] * inv); o1.y = f2b(v[5] * inv); o1.z = f2b(v[6] * inv); o1.w = f2b(v[7] * inv);
    ushort4* p4 = (ushort4*)(P + row * C) + tid * 2;
    p4[0] = o0;
    p4[1] = o1;
}

// ---------------- fused residual(+partial-sum) + LayerNorm (D=1024) ----------------
// out = LN(X + Y + (Y2?)) ; Y2 nullable (split-K partial reduction fused here).

__global__ __launch_bounds__(256) void residual_ln(const float* __restrict__ X,
                                                   const float* __restrict__ Y,
                                                   const float* __restrict__ Y2,
                                                   const float* __restrict__ g,
                                                   const float* __restrict__ be,
                                                   float* __restrict__ outf,
                                                   ushort* __restrict__ outb) {
    const int D = 1024;
    const long long row = blockIdx.x;
    const float* x = X + row * D;
    const float* y = Y + row * D;
    const float* y2 = Y2 ? Y2 + row * D : nullptr;
    const int tid = threadIdx.x;
    float v[4];
    float s = 0.f, s2 = 0.f;
#pragma unroll
    for (int i = 0; i < 4; i++) {
        int c = tid + i * 256;
        float t = x[c] + y[c];
        if (y2) t += y2[c];
        v[i] = t;
        s += t;
        s2 += t * t;
    }
    __shared__ float r1[256], r2[256];
    r1[tid] = s;
    r2[tid] = s2;
    __syncthreads();
    for (int off = 128; off > 0; off >>= 1) {
        if (tid < off) {
            r1[tid] += r1[tid + off];
            r2[tid] += r2[tid + off];
        }
        __syncthreads();
    }
    float mu = r1[0] * (1.f / 1024.f);
    float var = r2[0] * (1.f / 1024.f) - mu * mu;
    float inv = rsqrtf(var + 1e-5f);
    float* of = outf + row * D;
    ushort* ob = outb ? outb + row * D : nullptr;
#pragma unroll
    for (int i = 0; i < 4; i++) {
        int c = tid + i * 256;
        float o = (v[i] - mu) * inv * g[c] + be[c];
        of[c] = o;
        if (ob) ob[c] = f2b(o);
    }
}

// ---------------- launch ----------------

extern "C" void kernel_launch(void* const* d_in, const int* in_sizes, int n_in,
                              void* d_out, int out_size, void* d_ws, size_t ws_size,
                              hipStream_t stream) {
    const float* x  = (const float*)d_in[0];
    const float* wq = (const float*)d_in[1];
    const float* bq = (const float*)d_in[2];
    const float* wk = (const float*)d_in[3];
    const float* bk = (const float*)d_in[4];
    const float* wv = (const float*)d_in[5];
    const float* bv = (const float*)d_in[6];
    const float* wo = (const float*)d_in[7];
    const float* bo = (const float*)d_in[8];
    const float* w1 = (const float*)d_in[9];
    const float* b1 = (const float*)d_in[10];
    const float* w2 = (const float*)d_in[11];
    const float* b2 = (const float*)d_in[12];
    const float* g1 = (const float*)d_in[13];
    const float* be1 = (const float*)d_in[14];
    const float* g2 = (const float*)d_in[15];
    const float* be2 = (const float*)d_in[16];
    float* out = (float*)d_out;
    char* ws = (char*)d_ws;

    const int Bz = 4, S = 2048, D = 1024, F = 4096;
    const int T = Bz * S;  // 8192 rows
    const size_t MBy = 1024ull * 1024ull;

    // workspace layout (byte offsets), lifetime-based reuse; peak 201 MB
    ushort* qkvT = (ushort*)(ws + 0);        // 6 MB   [3072][1024] fused wq/wk/wv^T
    ushort* woT  = (ushort*)(ws + 6 * MBy);  // 2 MB
    ushort* w1T  = (ushort*)(ws + 8 * MBy);  // 8 MB   [F][D]
    ushort* w2T  = (ushort*)(ws + 16 * MBy); // 8 MB   [D][F]
    float*  bqkv = (float*)(ws + 24 * MBy);  // 12 KB  (dead after QKV gemm)
    ushort* xb   = (ushort*)(ws + 25 * MBy); // 16 MB  (dead after QKV gemm)
    ushort* qkv  = (ushort*)(ws + 41 * MBy); // 48 MB  [T][3072] (dead after scores+vT)
    ushort* vT   = (ushort*)(ws + 89 * MBy); // 16 MB  [B][D][S] (dead after ctx)
    ushort* scb  = (ushort*)(ws + 105 * MBy); // 32 MB bf16 scores (dead after softmax)
    ushort* attn = (ushort*)(ws + 169 * MBy); // 32 MB (dead after ctx)
    // reuse (non-overlapping lifetimes):
    ushort* ctx = (ushort*)(ws + 25 * MBy);  // 16 MB over xb/bqkv (dead after wo)
    float*  ao0 = (float*)(ws + 105 * MBy);  // 32 MB over scb (dead after ln1)
    float*  ao1 = (float*)(ws + 137 * MBy);  // 32 MB (dead after ln1)
    float*  x1  = (float*)(ws + 41 * MBy);   // 32 MB over qkv (live to ln2)
    ushort* x1b = (ushort*)(ws + 73 * MBy);  // 16 MB over qkv (dead after ffn1)
    ushort* h   = (ushort*)(ws + 105 * MBy); // 64 MB over scb/ao (after ln1)
    float*  ff0 = (float*)(ws + 169 * MBy);  // 32 MB over attn
    float*  ff1 = (float*)(ws + 73 * MBy);   // 32 MB over x1b+vT (both dead by ffn2)

    dim3 b32(32, 8);

    // 1) cast x -> bf16
    cast_f2b4<<<(T * D) / 1024, 256, 0, stream>>>(x, xb, (long long)(T * D) / 4);

    // 2) transpose-cast weights: wq/wk/wv stacked into qkvT [3072][1024]
    transpose_to_bf16<float><<<dim3(32, 32, 1), b32, 0, stream>>>(wq, qkvT, D, D, D, 0, 0);
    transpose_to_bf16<float><<<dim3(32, 32, 1), b32, 0, stream>>>(wk, qkvT + 1024 * 1024, D, D, D, 0, 0);
    transpose_to_bf16<float><<<dim3(32, 32, 1), b32, 0, stream>>>(wv, qkvT + 2048 * 1024, D, D, D, 0, 0);
    transpose_to_bf16<float><<<dim3(32, 32, 1), b32, 0, stream>>>(wo, woT, D, D, D, 0, 0);
    transpose_to_bf16<float><<<dim3(128, 32, 1), b32, 0, stream>>>(w1, w1T, D, F, F, 0, 0);
    transpose_to_bf16<float><<<dim3(32, 128, 1), b32, 0, stream>>>(w2, w2T, F, D, D, 0, 0);

    // 3) fused bias vector [bq|bk|bv]
    hipMemcpyAsync(bqkv, bq, D * sizeof(float), hipMemcpyDeviceToDevice, stream);
    hipMemcpyAsync(bqkv + D, bk, D * sizeof(float), hipMemcpyDeviceToDevice, stream);
    hipMemcpyAsync(bqkv + 2 * D, bv, D * sizeof(float), hipMemcpyDeviceToDevice, stream);

    // 4) fused QKV projection: [T][1024] x [3072][1024]^T -> [T][3072] bf16 (1536 blocks)
    gemm_bt<1, 0, 1><<<dim3(3 * D / 128, T / 128, 1), 256, 0, stream>>>(
        xb, qkvT, qkv, bqkv, 3 * D, D, 1, 1.f, D, D, 3 * D, 0, 0, 0, 0);

    // 5) V^T per batch: qkv v-slice [S][1024] (ld 3072) -> [D][S]
    transpose_to_bf16<ushort><<<dim3(D / 32, S / 32, Bz), b32, 0, stream>>>(
        qkv + 2048, vT, S, D, 3 * D, (long long)S * 3 * D, (long long)S * D);

    // 6) scores = Q K^T / 32 -> bf16; A=q, B=k slices of qkv (ld 3072)
    gemm_bt<1, 0, 0><<<dim3(S / 128, S / 128, Bz), 256, 0, stream>>>(
        qkv, qkv + 1024, scb, nullptr, S, D, 1, 0.03125f, 3 * D, 3 * D, S,
        (long long)S * 3 * D, (long long)S * 3 * D, (long long)S * S, 0);

    // 7) softmax rows -> bf16 attn
    softmax_rows<<<T, 256, 0, stream>>>(scb, attn);

    // 8) ctx = attn @ V  (BT = V^T [D][S]) -> bf16 [S][D] per batch
    gemm_bt<1, 0, 0><<<dim3(D / 128, S / 128, Bz), 256, 0, stream>>>(
        attn, vT, ctx, nullptr, D, S, 1, 1.f, S, S, D,
        (long long)S * S, (long long)D * S, (long long)S * D, 0);

    // 9) attn_out partials = ctx @ wo^T (+bo chunk 0), split-K=2, plain stores (1024 blocks)
    gemm_bt<0, 0, 1><<<dim3(D / 128, T / 128, 2), 256, 0, stream>>>(
        ctx, woT, ao0, bo, D, D, 2, 1.f, D, D, D, 0, 0, 0, (long long)(ao1 - ao0));

    // 10) x1 = LN(x + ao0 + ao1) -> fp32 + bf16 (split-K reduction fused)
    residual_ln<<<T, 256, 0, stream>>>(x, ao0, ao1, g1, be1, x1, x1b);

    // 11) h = relu(x1 @ w1 + b1) (bf16, 2048 blocks)
    gemm_bt<1, 1, 1><<<dim3(F / 128, T / 128, 1), 256, 0, stream>>>(
        x1b, w1T, h, b1, F, D, 1, 1.f, D, D, F, 0, 0, 0, 0);

    // 12) ff partials = h @ w2 (+b2 on chunk 0), split-K=2, plain stores (1024 blocks)
    gemm_bt<0, 0, 1><<<dim3(D / 128, T / 128, 2), 256, 0, stream>>>(
        h, w2T, ff0, b2, D, F, 2, 1.f, F, F, D, 0, 0, 0, (long long)(ff1 - ff0));

    // 13) out = LN(x1 + ff0 + ff1) -> d_out fp32 (split-K reduction fused)
    residual_ln<<<T, 256, 0, stream>>>(x1, ff0, ff1, g2, be2, out, nullptr);
}

// Round 7
// 595.742 us; speedup vs baseline: 1.2566x; 1.0521x over previous
//
#include <hip/hip_runtime.h>
#include <stdint.h>

// ---------------- common helpers ----------------

using f32x4 = __attribute__((ext_vector_type(4))) float;
using s16x8 = __attribute__((ext_vector_type(8))) short;

__device__ __forceinline__ ushort f2b(float f) {
    union { float f; uint32_t u; } v; v.f = f;
    uint32_t u = v.u;
    return (ushort)((u + 0x7fffu + ((u >> 16) & 1u)) >> 16);
}
__device__ __forceinline__ float b2f(ushort b) {
    union { uint32_t u; float f; } v; v.u = ((uint32_t)b) << 16;
    return v.f;
}
__device__ __forceinline__ float to_f(float f) { return f; }
__device__ __forceinline__ float to_f(ushort b) { return b2f(b); }

// async global->LDS, 16B per lane; LDS dest = wave-uniform base + lane*16
__device__ __forceinline__ void async_ld16(const ushort* g, ushort* l) {
    __builtin_amdgcn_global_load_lds(
        (const __attribute__((address_space(1))) void*)g,
        (__attribute__((address_space(3))) void*)l,
        16, 0, 0);
}

// s_waitcnt immediates (gfx9 encoding): vmcnt[3:0]|[15:14], expcnt[6:4], lgkmcnt[11:8]
#define WAITCNT_VM4 0x0F74  // vmcnt=4, lgkm/exp no-wait
#define WAITCNT_VM0 0x0F70  // vmcnt=0

// ---------------- cast fp32 -> bf16 (vectorized x4) ----------------

__global__ __launch_bounds__(256) void cast_f2b4(const float* __restrict__ src,
                                                 ushort* __restrict__ dst,
                                                 long long n4) {
    long long i = (long long)blockIdx.x * 256 + threadIdx.x;
    if (i >= n4) return;
    float4 f = ((const float4*)src)[i];
    ushort4 o;
    o.x = f2b(f.x); o.y = f2b(f.y); o.z = f2b(f.z); o.w = f2b(f.w);
    ((ushort4*)dst)[i] = o;
}

// ---------------- bias concat: [bq|bk|bv] -> dst (3*1024 floats) ----------------

__global__ __launch_bounds__(256) void concat3(const float* __restrict__ a,
                                               const float* __restrict__ b,
                                               const float* __restrict__ c,
                                               float* __restrict__ dst) {
    int i = blockIdx.x * 256 + threadIdx.x;  // grid 12 blocks = 3072
    const float* s = (i < 1024) ? a : (i < 2048) ? b : c;
    dst[i] = s[i & 1023];
}

// ---------------- transpose (fp32 or bf16 in) -> bf16 out ----------------
// src: [R][C] with row stride srcLd, dst: [C][R] row-major.
// Grid: (C/32, R/32, batch), block (32,8).

template <typename T>
__global__ __launch_bounds__(256) void transpose_to_bf16(const T* __restrict__ src,
                                                         ushort* __restrict__ dst,
                                                         int R, int C, int srcLd,
                                                         long long ss, long long ds) {
    __shared__ float tile[32][33];
    src += (long long)blockIdx.z * ss;
    dst += (long long)blockIdx.z * ds;
    const int c0 = blockIdx.x * 32;
    const int r0 = blockIdx.y * 32;
    const int tx = threadIdx.x, ty = threadIdx.y;
#pragma unroll
    for (int i = 0; i < 4; i++) {
        int r = r0 + ty + i * 8;
        tile[ty + i * 8][tx] = to_f(src[(long long)r * srcLd + c0 + tx]);
    }
    __syncthreads();
#pragma unroll
    for (int i = 0; i < 4; i++) {
        int r = c0 + ty + i * 8;  // row of dst, in [0, C)
        dst[(long long)r * R + r0 + tx] = f2b(tile[tx][ty + i * 8]);
    }
}

// ---- fused 4x (1024x1024) transpose-cast: z selects {wq,wk,wv,wo}, dst contiguous ----

__global__ __launch_bounds__(256) void transpose4_to_bf16(const float* __restrict__ s0,
                                                          const float* __restrict__ s1,
                                                          const float* __restrict__ s2,
                                                          const float* __restrict__ s3,
                                                          ushort* __restrict__ dst) {
    __shared__ float tile[32][33];
    const int D = 1024;
    const int z = blockIdx.z;
    const float* src = (z == 0) ? s0 : (z == 1) ? s1 : (z == 2) ? s2 : s3;
    dst += (long long)z * D * D;
    const int c0 = blockIdx.x * 32;
    const int r0 = blockIdx.y * 32;
    const int tx = threadIdx.x, ty = threadIdx.y;
#pragma unroll
    for (int i = 0; i < 4; i++) {
        int r = r0 + ty + i * 8;
        tile[ty + i * 8][tx] = src[(long long)r * D + c0 + tx];
    }
    __syncthreads();
#pragma unroll
    for (int i = 0; i < 4; i++) {
        int r = c0 + ty + i * 8;
        dst[(long long)r * D + r0 + tx] = f2b(tile[tx][ty + i * 8]);
    }
}

// ---------------- bf16 MFMA GEMM:  C[M,N] = A[M,K] * BT[N,K]^T (+bias, relu, scale) ----
// 128x128 tile per 256-thread block (4 waves, each 64x64 = 4x4 MFMA 16x16x32 tiles).
// Staging via global_load_lds width=16: UNPADDED LDS [row][32], wave w instr i covers
// rows w*32+i*16..+16; lane l -> row +(l>>2), col (l&3)*8.
// 2-stage double-buffered pipeline (R5 structure; R6's 3-stage was neutral) with
// __launch_bounds__(256,4): force <=128 total regs (64 acc + ~64) -> 4 blocks/CU.
// LDS 32 KB allows 5 blocks/CU; regs bind at 4 (R6 evidence: occupancy ~23% at
// 140 regs / 3 blocks was the limiter, not load latency).
// Grid: (N/128, M/128, batch*kChunks). gridDim.y must be a multiple of 8 (XCD swizzle).
// Split-K (kChunks>1): chunk kIdx writes partial (plain stores, NO atomics) at
// C + kIdx*sK; bias on chunk 0 only; reduction fused into downstream residual_ln.

#define BM 128
#define BN 128
#define BKK 32
#define TILE_ELEMS (BM * BKK)  // 4096

template <int OUT_BF16, int RELU, int HAS_BIAS>
__global__ __launch_bounds__(256, 4) void gemm_bt(const ushort* __restrict__ A,
                                                  const ushort* __restrict__ BT,
                                                  void* __restrict__ Cp,
                                                  const float* __restrict__ bias,
                                                  int N, int K, int kChunks, float scale,
                                                  int lda, int ldb, int ldc,
                                                  long long sA, long long sB, long long sC,
                                                  long long sK) {
    __shared__ ushort As[2 * TILE_ELEMS];  // 16 KB
    __shared__ ushort Bs[2 * TILE_ELEMS];  // 16 KB

    const int tid = threadIdx.x;
    const int kIdx = blockIdx.z % kChunks;
    const int bz = blockIdx.z / kChunks;
    const int kLen = K / kChunks;
    const int kOff = kIdx * kLen;
    const ushort* Ab = A + (long long)bz * sA;
    const ushort* Bb = BT + (long long)bz * sB;

    // XCD-panel swizzle (R3 evidence: FETCH 269->74 MB on FFN2). Keep.
    const int W = gridDim.x, H = gridDim.y;
    const int b = blockIdx.y * W + blockIdx.x;
    const int Hp = H >> 3;
    const int xcd = b & 7;
    const int s = b >> 3;
    const int tn = s / Hp;
    const int tm = xcd * Hp + (s % Hp);

    const int lane = tid & 63;
    const int wave = tid >> 6;
    const int wm = (wave >> 1) * 64;
    const int wn = (wave & 1) * 64;
    const int quad = lane >> 4;
    const int l16 = lane & 15;

    // async staging addresses: wave covers rows [wave*32, wave*32+32)
    const int srow = wave * 32 + (lane >> 2);  // instr 1 adds 16 rows
    const int scol = (lane & 3) * 8;
    const ushort* AgL = Ab + (long long)(tm * BM + srow) * lda + scol + kOff;
    const ushort* BgL = Bb + (long long)(tn * BN + srow) * ldb + scol + kOff;
    ushort* AsL = As + wave * 1024;  // per-buffer wave base; instr 1 adds 512 elems
    ushort* BsL = Bs + wave * 1024;
    const long long rstepA = (long long)16 * lda;
    const long long rstepB = (long long)16 * ldb;

    f32x4 acc[4][4];
#pragma unroll
    for (int i = 0; i < 4; i++)
#pragma unroll
        for (int j = 0; j < 4; j++) acc[i][j] = (f32x4){0.f, 0.f, 0.f, 0.f};

    // prologue: issue tile 0 into buffer 0
    async_ld16(AgL, AsL);
    async_ld16(AgL + rstepA, AsL + 512);
    async_ld16(BgL, BsL);
    async_ld16(BgL + rstepB, BsL + 512);

    int p = 0;
    for (int k0 = 0; k0 < kLen; k0 += BKK) {
        // issue tile k+1 into alternate buffer, then wait only for tile k (4 oldest)
        if (k0 + BKK < kLen) {
            const int q = p ^ 1;
            async_ld16(AgL + (k0 + BKK), AsL + q * TILE_ELEMS);
            async_ld16(AgL + rstepA + (k0 + BKK), AsL + q * TILE_ELEMS + 512);
            async_ld16(BgL + (k0 + BKK), BsL + q * TILE_ELEMS);
            async_ld16(BgL + rstepB + (k0 + BKK), BsL + q * TILE_ELEMS + 512);
            __builtin_amdgcn_s_waitcnt(WAITCNT_VM4);
        } else {
            __builtin_amdgcn_s_waitcnt(WAITCNT_VM0);
        }
        __builtin_amdgcn_s_barrier();  // tile k visible to all; k+1 stays in flight

        const ushort* Asp = As + p * TILE_ELEMS;
        const ushort* Bsp = Bs + p * TILE_ELEMS;
        s16x8 af[4], bf[4];
#pragma unroll
        for (int i = 0; i < 4; i++)
            af[i] = *(const s16x8*)&Asp[(wm + i * 16 + l16) * BKK + quad * 8];
#pragma unroll
        for (int j = 0; j < 4; j++)
            bf[j] = *(const s16x8*)&Bsp[(wn + j * 16 + l16) * BKK + quad * 8];
#pragma unroll
        for (int i = 0; i < 4; i++)
#pragma unroll
            for (int j = 0; j < 4; j++)
                acc[i][j] = __builtin_amdgcn_mfma_f32_16x16x32_bf16(af[i], bf[j], acc[i][j], 0, 0, 0);

        __builtin_amdgcn_s_barrier();  // all reads of buf p done -> next iter may DMA it
        p ^= 1;
    }

    // epilogue: C/D layout col = lane&15, row = quad*4 + reg  [verified m89/m91]
    const long long cb = (long long)bz * sC + (long long)kIdx * sK;
    float* Cf = (float*)Cp;
    ushort* Cb = (ushort*)Cp;
#pragma unroll
    for (int j = 0; j < 4; j++) {
        const int col = tn * BN + wn + j * 16 + l16;
        float bv = (HAS_BIAS && kIdx == 0) ? bias[col] : 0.0f;
#pragma unroll
        for (int i = 0; i < 4; i++) {
            const int row0 = tm * BM + wm + i * 16 + quad * 4;
#pragma unroll
            for (int r = 0; r < 4; r++) {
                float v = acc[i][j][r] * scale + bv;
                if (RELU) v = v > 0.f ? v : 0.f;
                long long idx = cb + (long long)(row0 + r) * ldc + col;
                if (OUT_BF16) Cb[idx] = f2b(v);
                else Cf[idx] = v;
            }
        }
    }
}

// ---------------- row softmax: bf16 [rows][2048] -> bf16, vectorized 8/thread -------

__global__ __launch_bounds__(256) void softmax_rows(const ushort* __restrict__ S,
                                                    ushort* __restrict__ P) {
    const int C = 2048;
    const long long row = blockIdx.x;
    const int tid = threadIdx.x;
    const ushort4* s4 = (const ushort4*)(S + row * C) + tid * 2;  // 8 contiguous elems
    ushort4 a = s4[0], bq = s4[1];
    float v[8];
    v[0] = b2f(a.x); v[1] = b2f(a.y); v[2] = b2f(a.z); v[3] = b2f(a.w);
    v[4] = b2f(bq.x); v[5] = b2f(bq.y); v[6] = b2f(bq.z); v[7] = b2f(bq.w);
    float mx = -1e30f;
#pragma unroll
    for (int i = 0; i < 8; i++) mx = fmaxf(mx, v[i]);
    __shared__ float red[256];
    red[tid] = mx;
    __syncthreads();
    for (int off = 128; off > 0; off >>= 1) {
        if (tid < off) red[tid] = fmaxf(red[tid], red[tid + off]);
        __syncthreads();
    }
    mx = red[0];
    __syncthreads();
    float sum = 0.f;
#pragma unroll
    for (int i = 0; i < 8; i++) {
        v[i] = __expf(v[i] - mx);
        sum += v[i];
    }
    red[tid] = sum;
    __syncthreads();
    for (int off = 128; off > 0; off >>= 1) {
        if (tid < off) red[tid] += red[tid + off];
        __syncthreads();
    }
    float inv = 1.f / red[0];
    ushort4 o0, o1;
    o0.x = f2b(v[0] * inv); o0.y = f2b(v[1] * inv); o0.z = f2b(v[2] * inv); o0.w = f2b(v[3] * inv);
    o1.x = f2b(v[4] * inv); o1.y = f2b(v[5] * inv); o1.z = f2b(v[6] * inv); o1.w = f2b(v[7] * inv);
    ushort4* p4 = (ushort4*)(P + row * C) + tid * 2;
    p4[0] = o0;
    p4[1] = o1;
}

// ---------------- fused residual(+partial-sum) + LayerNorm (D=1024) ----------------
// out = LN(X + Y + (Y2?)) ; Y2 nullable (split-K partial reduction fused here).

__global__ __launch_bounds__(256) void residual_ln(const float* __restrict__ X,
                                                   const float* __restrict__ Y,
                                                   const float* __restrict__ Y2,
                                                   const float* __restrict__ g,
                                                   const float* __restrict__ be,
                                                   float* __restrict__ outf,
                                                   ushort* __restrict__ outb) {
    const int D = 1024;
    const long long row = blockIdx.x;
    const float* x = X + row * D;
    const float* y = Y + row * D;
    const float* y2 = Y2 ? Y2 + row * D : nullptr;
    const int tid = threadIdx.x;
    float v[4];
    float s = 0.f, s2 = 0.f;
#pragma unroll
    for (int i = 0; i < 4; i++) {
        int c = tid + i * 256;
        float t = x[c] + y[c];
        if (y2) t += y2[c];
        v[i] = t;
        s += t;
        s2 += t * t;
    }
    __shared__ float r1[256], r2[256];
    r1[tid] = s;
    r2[tid] = s2;
    __syncthreads();
    for (int off = 128; off > 0; off >>= 1) {
        if (tid < off) {
            r1[tid] += r1[tid + off];
            r2[tid] += r2[tid + off];
        }
        __syncthreads();
    }
    float mu = r1[0] * (1.f / 1024.f);
    float var = r2[0] * (1.f / 1024.f) - mu * mu;
    float inv = rsqrtf(var + 1e-5f);
    float* of = outf + row * D;
    ushort* ob = outb ? outb + row * D : nullptr;
#pragma unroll
    for (int i = 0; i < 4; i++) {
        int c = tid + i * 256;
        float o = (v[i] - mu) * inv * g[c] + be[c];
        of[c] = o;
        if (ob) ob[c] = f2b(o);
    }
}

// ---------------- launch ----------------

extern "C" void kernel_launch(void* const* d_in, const int* in_sizes, int n_in,
                              void* d_out, int out_size, void* d_ws, size_t ws_size,
                              hipStream_t stream) {
    const float* x  = (const float*)d_in[0];
    const float* wq = (const float*)d_in[1];
    const float* bq = (const float*)d_in[2];
    const float* wk = (const float*)d_in[3];
    const float* bk = (const float*)d_in[4];
    const float* wv = (const float*)d_in[5];
    const float* bv = (const float*)d_in[6];
    const float* wo = (const float*)d_in[7];
    const float* bo = (const float*)d_in[8];
    const float* w1 = (const float*)d_in[9];
    const float* b1 = (const float*)d_in[10];
    const float* w2 = (const float*)d_in[11];
    const float* b2 = (const float*)d_in[12];
    const float* g1 = (const float*)d_in[13];
    const float* be1 = (const float*)d_in[14];
    const float* g2 = (const float*)d_in[15];
    const float* be2 = (const float*)d_in[16];
    float* out = (float*)d_out;
    char* ws = (char*)d_ws;

    const int Bz = 4, S = 2048, D = 1024, F = 4096;
    const int T = Bz * S;  // 8192 rows
    const size_t MBy = 1024ull * 1024ull;

    // workspace layout (byte offsets), lifetime-based reuse; peak 201 MB
    ushort* qkvT = (ushort*)(ws + 0);        // 6 MB  [3072][1024]; woT follows contiguously
    ushort* woT  = (ushort*)(ws + 6 * MBy);  // 2 MB
    ushort* w1T  = (ushort*)(ws + 8 * MBy);  // 8 MB   [F][D]
    ushort* w2T  = (ushort*)(ws + 16 * MBy); // 8 MB   [D][F]
    float*  bqkv = (float*)(ws + 24 * MBy);  // 12 KB  (dead after QKV gemm)
    ushort* xb   = (ushort*)(ws + 25 * MBy); // 16 MB  (dead after QKV gemm)
    ushort* qkv  = (ushort*)(ws + 41 * MBy); // 48 MB  [T][3072] (dead after scores+vT)
    ushort* vT   = (ushort*)(ws + 89 * MBy); // 16 MB  [B][D][S] (dead after ctx)
    ushort* scb  = (ushort*)(ws + 105 * MBy); // 32 MB bf16 scores (dead after softmax)
    ushort* attn = (ushort*)(ws + 169 * MBy); // 32 MB (dead after ctx)
    // reuse (non-overlapping lifetimes):
    ushort* ctx = (ushort*)(ws + 25 * MBy);  // 16 MB over xb/bqkv (dead after wo)
    float*  ao0 = (float*)(ws + 105 * MBy);  // 32 MB over scb (dead after ln1)
    float*  ao1 = (float*)(ws + 137 * MBy);  // 32 MB (dead after ln1)
    float*  x1  = (float*)(ws + 41 * MBy);   // 32 MB over qkv (live to ln2)
    ushort* x1b = (ushort*)(ws + 73 * MBy);  // 16 MB over qkv (dead after ffn1)
    ushort* h   = (ushort*)(ws + 105 * MBy); // 64 MB over scb/ao (after ln1)
    float*  ff0 = (float*)(ws + 169 * MBy);  // 32 MB over attn
    float*  ff1 = (float*)(ws + 73 * MBy);   // 32 MB over x1b+vT (both dead by ffn2)

    dim3 b32(32, 8);

    // 1) cast x -> bf16
    cast_f2b4<<<(T * D) / 1024, 256, 0, stream>>>(x, xb, (long long)(T * D) / 4);

    // 2) transpose-cast weights: wq/wk/wv/wo -> [qkvT|woT] in ONE dispatch; w1, w2
    transpose4_to_bf16<<<dim3(32, 32, 4), b32, 0, stream>>>(wq, wk, wv, wo, qkvT);
    transpose_to_bf16<float><<<dim3(128, 32, 1), b32, 0, stream>>>(w1, w1T, D, F, F, 0, 0);
    transpose_to_bf16<float><<<dim3(32, 128, 1), b32, 0, stream>>>(w2, w2T, F, D, D, 0, 0);

    // 3) fused bias vector [bq|bk|bv]
    concat3<<<12, 256, 0, stream>>>(bq, bk, bv, bqkv);

    // 4) fused QKV projection: [T][1024] x [3072][1024]^T -> [T][3072] bf16 (1536 blocks)
    gemm_bt<1, 0, 1><<<dim3(3 * D / 128, T / 128, 1), 256, 0, stream>>>(
        xb, qkvT, qkv, bqkv, 3 * D, D, 1, 1.f, D, D, 3 * D, 0, 0, 0, 0);

    // 5) V^T per batch: qkv v-slice [S][1024] (ld 3072) -> [D][S]
    transpose_to_bf16<ushort><<<dim3(D / 32, S / 32, Bz), b32, 0, stream>>>(
        qkv + 2048, vT, S, D, 3 * D, (long long)S * 3 * D, (long long)S * D);

    // 6) scores = Q K^T / 32 -> bf16; A=q, B=k slices of qkv (ld 3072)
    gemm_bt<1, 0, 0><<<dim3(S / 128, S / 128, Bz), 256, 0, stream>>>(
        qkv, qkv + 1024, scb, nullptr, S, D, 1, 0.03125f, 3 * D, 3 * D, S,
        (long long)S * 3 * D, (long long)S * 3 * D, (long long)S * S, 0);

    // 7) softmax rows -> bf16 attn
    softmax_rows<<<T, 256, 0, stream>>>(scb, attn);

    // 8) ctx = attn @ V  (BT = V^T [D][S]) -> bf16 [S][D] per batch
    gemm_bt<1, 0, 0><<<dim3(D / 128, S / 128, Bz), 256, 0, stream>>>(
        attn, vT, ctx, nullptr, D, S, 1, 1.f, S, S, D,
        (long long)S * S, (long long)D * S, (long long)S * D, 0);

    // 9) attn_out partials = ctx @ wo^T (+bo chunk 0), split-K=2, plain stores (1024 blocks)
    gemm_bt<0, 0, 1><<<dim3(D / 128, T / 128, 2), 256, 0, stream>>>(
        ctx, woT, ao0, bo, D, D, 2, 1.f, D, D, D, 0, 0, 0, (long long)(ao1 - ao0));

    // 10) x1 = LN(x + ao0 + ao1) -> fp32 + bf16 (split-K reduction fused)
    residual_ln<<<T, 256, 0, stream>>>(x, ao0, ao1, g1, be1, x1, x1b);

    // 11) h = relu(x1 @ w1 + b1) (bf16, 2048 blocks)
    gemm_bt<1, 1, 1><<<dim3(F / 128, T / 128, 1), 256, 0, stream>>>(
        x1b, w1T, h, b1, F, D, 1, 1.f, D, D, F, 0, 0, 0, 0);

    // 12) ff partials = h @ w2 (+b2 on chunk 0), split-K=2, plain stores (1024 blocks)
    gemm_bt<0, 0, 1><<<dim3(D / 128, T / 128, 2), 256, 0, stream>>>(
        h, w2T, ff0, b2, D, F, 2, 1.f, F, F, D, 0, 0, 0, (long long)(ff1 - ff0));

    // 13) out = LN(x1 + ff0 + ff1) -> d_out fp32 (split-K reduction fused)
    residual_ln<<<T, 256, 0, stream>>>(x1, ff0, ff1, g2, be2, out, nullptr);
}